// Round 2
// baseline (413.247 us; speedup 1.0000x reference)
//
#include <hip/hip_runtime.h>
#include <hip/hip_fp16.h>
#include <cstdint>
#include <cstddef>

#define NN 100000
#define NE 1600000
#define NEP (NE + NN)              // 1,700,000
#define NBLK 200                   // partition blocks
#define CHUNK ((NEP + NBLK - 1) / NBLK)   // 8500
#define NBUCK2 ((NN + 255) / 256)  // 391 buckets of 256 dst nodes
#define HISTN (NBUCK2 * NBLK)      // 78,200
#define HSCAN_BLOCKS ((HISTN + 1023) / 1024)  // 77

typedef __attribute__((ext_vector_type(8))) _Float16 half8;
typedef __attribute__((ext_vector_type(4))) _Float16 h4v;
typedef __attribute__((ext_vector_type(2))) _Float16 h2v;
typedef __attribute__((ext_vector_type(4))) float float4v;

__device__ __forceinline__ float elu_f(float x) {
    return x > 0.f ? x : __expf(x) - 1.f;
}

__device__ __forceinline__ float ex2(float x) {
#if __has_builtin(__builtin_amdgcn_exp2f)
    return __builtin_amdgcn_exp2f(x);
#else
    return exp2f(x);
#endif
}

// ---- DPP reduce helpers (pure VALU) ----
template<int CTRL>
__device__ __forceinline__ float dpp_add(float x) {
    int s = __builtin_amdgcn_update_dpp(0, __float_as_int(x), CTRL, 0xF, 0xF, true);
    return x + __int_as_float(s);
}
// allsum within aligned 4-lane quads (one GAT1 head = 4 lanes x 8ch)
__device__ __forceinline__ float sum4_all(float x) {
    x = dpp_add<0xB1>(x); x = dpp_add<0x4E>(x);
    return x;
}
// allsum within aligned 8-lane groups (one GAT2 edge = 8 lanes x 4ch)
__device__ __forceinline__ float sum8_all(float x) {
    x = dpp_add<0xB1>(x); x = dpp_add<0x4E>(x); x = dpp_add<0x141>(x);
    return x;
}

__device__ __forceinline__ float dot2f(h2v a, h2v b, float c) {
#if __has_builtin(__builtin_amdgcn_fdot2)
    return __builtin_amdgcn_fdot2(a, b, c, false);
#else
    return fmaf((float)a[0], (float)b[0], fmaf((float)a[1], (float)b[1], c));
#endif
}

__device__ __forceinline__ h2v hmax2v(h2v a, h2v b) {
#if __has_builtin(__builtin_elementwise_max)
    return __builtin_elementwise_max(a, b);
#else
    __half2 r = __hmax2(*(__half2*)&a, *(__half2*)&b);
    return *(h2v*)&r;
#endif
}

// ================= CSR build: deterministic radix partition =================

__global__ __launch_bounds__(256) void part_hist(const int* __restrict__ ei, int* __restrict__ hist)
{
    __shared__ int cnt[NBUCK2];
    int tid = threadIdx.x, k = blockIdx.x;
    for (int i = tid; i < NBUCK2; i += 256) cnt[i] = 0;
    __syncthreads();
    int e0 = k * CHUNK, e1 = min(e0 + CHUNK, NEP);
    for (int e = e0 + tid; e < e1; e += 256) {
        int dst = (e < NE) ? ei[NE + e] : e - NE;
        atomicAdd(&cnt[dst >> 8], 1);
    }
    __syncthreads();
    for (int i = tid; i < NBUCK2; i += 256) hist[i * NBLK + k] = cnt[i];
}

__global__ __launch_bounds__(256) void scan_p1(const int* __restrict__ src, int* __restrict__ part, int n)
{
    __shared__ int wsum[4];
    int t = threadIdx.x;
    int i0 = blockIdx.x * 1024 + t * 4;
    int s = 0;
    if (i0 + 3 < n) { int4 d = *(const int4*)(src + i0); s = d.x + d.y + d.z + d.w; }
    else { for (int k = 0; k < 4; k++) if (i0 + k < n) s += src[i0 + k]; }
    for (int d = 1; d < 64; d <<= 1) s += __shfl_xor(s, d, 64);
    if ((t & 63) == 0) wsum[t >> 6] = s;
    __syncthreads();
    if (t == 0) part[blockIdx.x] = wsum[0] + wsum[1] + wsum[2] + wsum[3];
}

__global__ __launch_bounds__(128) void scan_p2(int* __restrict__ part, int nb, int* __restrict__ off)
{
    __shared__ int wt[2];
    int t = threadIdx.x;
    int lane = t & 63, w = t >> 6;
    int v = (t < nb) ? part[t] : 0;
    int x = v;
    for (int d = 1; d < 64; d <<= 1) { int y = __shfl_up(x, d, 64); if (lane >= d) x += y; }
    if (lane == 63) wt[w] = x;
    __syncthreads();
    int base = (w == 1) ? wt[0] : 0;
    int excl = base + x - v;
    if (t < nb) part[t] = excl;
    if (t == 0) off[NN] = NEP;
}

__global__ __launch_bounds__(256) void scan_p3(int* __restrict__ data, const int* __restrict__ part, int n)
{
    __shared__ int wsum[4];
    int t = threadIdx.x, lane = t & 63, w = t >> 6;
    int i0 = blockIdx.x * 1024 + t * 4;
    int d0 = 0, d1 = 0, d2 = 0, d3 = 0;
    if (i0 + 3 < n) { int4 d = *(const int4*)(data + i0); d0 = d.x; d1 = d.y; d2 = d.z; d3 = d.w; }
    else if (i0 < n) {
        d0 = data[i0];
        if (i0 + 1 < n) d1 = data[i0 + 1];
        if (i0 + 2 < n) d2 = data[i0 + 2];
    }
    int s = d0 + d1 + d2 + d3;
    int x = s;
    for (int d = 1; d < 64; d <<= 1) { int y = __shfl_up(x, d, 64); if (lane >= d) x += y; }
    if (lane == 63) wsum[w] = x;
    __syncthreads();
    int wb = 0;
    for (int i = 0; i < w; i++) wb += wsum[i];
    int base = part[blockIdx.x] + wb + x - s;
    if (i0 < n)     data[i0]     = base;
    if (i0 + 1 < n) data[i0 + 1] = base + d0;
    if (i0 + 2 < n) data[i0 + 2] = base + d0 + d1;
    if (i0 + 3 < n) data[i0 + 3] = base + d0 + d1 + d2;
}

__global__ __launch_bounds__(256) void part_scatter(const int* __restrict__ ei,
                                                    const int* __restrict__ hist,
                                                    unsigned* __restrict__ ebuf)
{
    __shared__ int cur[NBUCK2];
    int tid = threadIdx.x, k = blockIdx.x;
    for (int i = tid; i < NBUCK2; i += 256) cur[i] = hist[i * NBLK + k];
    __syncthreads();
    int e0 = k * CHUNK, e1 = min(e0 + CHUNK, NEP);
    for (int e = e0 + tid; e < e1; e += 256) {
        int src, dst;
        if (e < NE) { src = ei[e]; dst = ei[NE + e]; } else { src = dst = e - NE; }
        int pos = atomicAdd(&cur[dst >> 8], 1);
        ebuf[pos] = (unsigned)src | ((unsigned)(dst & 255) << 24);
    }
}

__global__ __launch_bounds__(256) void bucket_csr(const int* __restrict__ hist,
                                                  const unsigned* __restrict__ ebuf,
                                                  int* __restrict__ off, int* __restrict__ csr)
{
    __shared__ int cnt[256];
    __shared__ int cur[256];
    __shared__ int wsum[4];
    int b = blockIdx.x;
    int d0 = b << 8;
    int tid = threadIdx.x;
    int e0 = hist[b * NBLK];
    int e1 = (b + 1 < NBUCK2) ? hist[(b + 1) * NBLK] : NEP;
    cnt[tid] = 0;
    __syncthreads();
    for (int i = e0 + tid; i < e1; i += 256) atomicAdd(&cnt[ebuf[i] >> 24], 1);
    __syncthreads();
    int c = cnt[tid];
    int x = c;
    int lane = tid & 63, w = tid >> 6;
    for (int d = 1; d < 64; d <<= 1) { int y = __shfl_up(x, d, 64); if (lane >= d) x += y; }
    if (lane == 63) wsum[w] = x;
    __syncthreads();
    int wb = 0;
    for (int i = 0; i < w; i++) wb += wsum[i];
    int excl = wb + x - c;
    cur[tid] = e0 + excl;
    int node = d0 + tid;
    if (node < NN) off[node] = e0 + excl;
    __syncthreads();
    for (int i = e0 + tid; i < e1; i += 256) {
        unsigned v = ebuf[i];
        int p = atomicAdd(&cur[v >> 24], 1);
        csr[p] = (int)(v & 0xFFFFFF);
    }
}

// ================= node feature prep (fp16 x [N][96]; bio + pca + pad fused) =================

__global__ __launch_bounds__(256) void bio_kernel(
    const float* __restrict__ xb, const float* __restrict__ xp,
    const float* __restrict__ W1, const float* __restrict__ b1,
    const float* __restrict__ g0, const float* __restrict__ bb0,
    const float* __restrict__ m0, const float* __restrict__ v0,
    const float* __restrict__ W2, const float* __restrict__ b2,
    __half* __restrict__ xh)
{
    __shared__ float sW1[16*64], sW2[16*16], sb1[16], sb2[16], ss[16], st[16];
    int tid = threadIdx.x;
    for (int idx = tid; idx < 1024; idx += 256) sW1[idx] = W1[idx];
    if (tid < 256) sW2[tid] = W2[tid];
    if (tid < 16) {
        sb1[tid] = b1[tid]; sb2[tid] = b2[tid];
        float s = g0[tid] * rsqrtf(v0[tid] + 1e-5f);
        ss[tid] = s; st[tid] = bb0[tid] - m0[tid] * s;
    }
    __syncthreads();
    int i = blockIdx.x * 256 + tid;
    if (i >= NN) return;
    float bio[64];
    const float4* p = (const float4*)(xb + (size_t)i * 64);
    #pragma unroll
    for (int q = 0; q < 16; q++) {
        float4 f = p[q];
        bio[q*4] = f.x; bio[q*4+1] = f.y; bio[q*4+2] = f.z; bio[q*4+3] = f.w;
    }
    float t1[16];
    #pragma unroll
    for (int j = 0; j < 16; j++) {
        float acc = sb1[j];
        #pragma unroll
        for (int k = 0; k < 64; k++) acc += bio[k] * sW1[j*64 + k];
        acc = acc * ss[j] + st[j];
        t1[j] = elu_f(acc);
    }
    __half* xrow = xh + (size_t)i * 96;
    const float* xpr = xp + (size_t)i * 50;
    #pragma unroll
    for (int j = 0; j < 25; j++) {
        float2 f = *(const float2*)(xpr + 2 * j);
        *(__half2*)(xrow + 2 * j) = __floats2half2_rn(f.x, f.y);
    }
    #pragma unroll
    for (int j = 0; j < 16; j++) {
        float acc = sb2[j];
        #pragma unroll
        for (int k = 0; k < 16; k++) acc += t1[k] * sW2[j*16 + k];
        xrow[50 + j] = __float2half(elu_f(acc));
    }
    __half2 z2 = __floats2half2_rn(0.f, 0.f);
    #pragma unroll
    for (int j = 0; j < 15; j++) *(__half2*)(xrow + 66 + 2 * j) = z2;
}

// ================= all weight conversions + BN/bias pre-fold in one launch =================

__global__ __launch_bounds__(256) void wconvert_all(
    const float* __restrict__ Wl1, const float* __restrict__ Wr1,
    const float* __restrict__ bl1, const float* __restrict__ br1,
    const float* __restrict__ Wl2, const float* __restrict__ Wr2,
    const float* __restrict__ bl2, const float* __restrict__ br2,
    const float* __restrict__ predW, const float* __restrict__ predb,
    const float* __restrict__ bias1, const float* __restrict__ bn1g,
    const float* __restrict__ bn1b, const float* __restrict__ bn1m,
    const float* __restrict__ bn1v,
    const float* __restrict__ bias2, const float* __restrict__ bn2g,
    const float* __restrict__ bn2b, const float* __restrict__ bn2m,
    const float* __restrict__ bn2v,
    __half* __restrict__ wcat1, float* __restrict__ bcat1,
    __half* __restrict__ wcat2, float* __restrict__ bcat2,
    __half* __restrict__ wpred, float* __restrict__ bpred,
    float* __restrict__ scb1, float* __restrict__ shb1,
    float* __restrict__ scb2, float* __restrict__ shb2)
{
    int t = blockIdx.x * 256 + threadIdx.x;
    if (t < 256 * 96) {
        int j = t / 96, k = t - j * 96;
        float v = (k < 66) ? ((j < 128) ? Wl1[j * 66 + k] : Wr1[(j - 128) * 66 + k]) : 0.f;
        wcat1[t] = __float2half(v);
    }
    int u = t - 256 * 96;
    if (u >= 0 && u < 64 * 128) {
        int j = u >> 7, k = u & 127;
        float v = (j < 32) ? Wl2[j * 128 + k] : Wr2[(j - 32) * 128 + k];
        wcat2[u] = __float2half(v);
    }
    int w = u - 64 * 128;
    if (w >= 0 && w < 64 * 32) {
        int j = w >> 5;
        wpred[w] = __float2half(j < 50 ? predW[w] : 0.f);
    }
    int z = w - 64 * 32;
    if (z >= 0 && z < 256) bcat1[z] = (z < 128) ? bl1[z] : br1[z - 128];
    int z2 = z - 256;
    if (z2 >= 0 && z2 < 64) bcat2[z2] = (z2 < 32) ? bl2[z2] : br2[z2 - 32];
    int z3 = z2 - 64;
    if (z3 >= 0 && z3 < 64) bpred[z3] = (z3 < 50) ? predb[z3] : 0.f;
    int z4 = z3 - 64;
    if (z4 >= 0 && z4 < 128) {
        float sc = bn1g[z4] * rsqrtf(bn1v[z4] + 1e-5f);
        scb1[z4] = sc;
        shb1[z4] = bn1b[z4] + (bias1[z4] - bn1m[z4]) * sc;
    }
    int z5 = z4 - 128;
    if (z5 >= 0 && z5 < 32) {
        float sc = bn2g[z5] * rsqrtf(bn2v[z5] + 1e-5f);
        scb2[z5] = sc;
        shb2[z5] = bn2b[z5] + (bias2[z5] - bn2m[z5]) * sc;
    }
}

// ================= MFMA f16 GEMM =================
template<int KT, int NC, bool FOUT>
__global__ __launch_bounds__(256) void mfma_gemm(
    const __half* __restrict__ in, const __half* __restrict__ wcat,
    const float* __restrict__ bcat, void* __restrict__ outv, int n, int ncol)
{
    constexpr int K = KT * 32;
    constexpr int KP = K + 8;
    __shared__ __half sW[NC * KP];
    __shared__ __half sX[64 * KP];
    __shared__ float sB[NC];
    int tid = threadIdx.x;
    for (int idx = tid * 8; idx < NC * K; idx += 256 * 8) {
        int r = idx / K, c = idx - r * K;
        *(half8*)(&sW[r * KP + c]) = *(const half8*)(&wcat[r * K + c]);
    }
    for (int idx = tid; idx < NC; idx += 256) sB[idx] = bcat[idx];
    int row0 = blockIdx.x * 64;
    half8 hz = {0, 0, 0, 0, 0, 0, 0, 0};
    for (int idx = tid * 8; idx < 64 * K; idx += 256 * 8) {
        int r = idx / K, c = idx - r * K;
        int gr = row0 + r;
        half8 v = (gr < n) ? *(const half8*)(&in[(size_t)gr * K + c]) : hz;
        *(half8*)(&sX[r * KP + c]) = v;
    }
    __syncthreads();
    int w = tid >> 6, lane = tid & 63;
    int m = lane & 15, quad = lane >> 4;
    half8 a[KT];
    #pragma unroll
    for (int kt = 0; kt < KT; kt++)
        a[kt] = *(const half8*)(&sX[(w * 16 + m) * KP + kt * 32 + quad * 8]);
    #pragma unroll 1
    for (int nt = 0; nt < NC / 16; nt++) {
        float4v acc = {0.f, 0.f, 0.f, 0.f};
        #pragma unroll
        for (int kt = 0; kt < KT; kt++) {
            half8 bfrag = *(const half8*)(&sW[(nt * 16 + m) * KP + kt * 32 + quad * 8]);
            acc = __builtin_amdgcn_mfma_f32_16x16x32_f16(a[kt], bfrag, acc, 0, 0, 0);
        }
        int col = nt * 16 + m;
        float bias = sB[col];
        #pragma unroll
        for (int i = 0; i < 4; i++) {
            int r = row0 + w * 16 + quad * 4 + i;
            if (r < n) {
                if (FOUT) { if (col < ncol) ((float*)outv)[(size_t)r * ncol + col] = acc[i] + bias; }
                else ((__half*)outv)[(size_t)r * NC + col] = __float2half(acc[i] + bias);
            }
        }
    }
}

// ================= fused GATv2 layer 1: 4 edges/iter x 16 lanes x 8ch =================
// xcat [N][256] fp16 (xl cols 0..127, xr 128..255). row=lane>>4 = edge slot,
// cl=lane&15, ch=8*cl. Head = 32 ch = 4 lanes = one aligned quad -> sum4_all.
// 3-pair software pipeline: all gathers for a <=24-edge node issue in the
// chunk prologue (6 x 256B in flight). Per-lane edge order identical to the
// depth-2 version, so accumulation order is unchanged.
// att is pre-scaled by log2(e): wgt = exp2(pp) == exp(logit).
// BN+bias pre-folded: o = elu(acc*inv*sc + sh).
__global__ __launch_bounds__(256) void fused_gat1(
    const int* __restrict__ off, const int* __restrict__ csr,
    const __half* __restrict__ xcat, const float* __restrict__ att,
    const float* __restrict__ scb, const float* __restrict__ shb,
    __half* __restrict__ h1)
{
    int wave = threadIdx.x >> 6;
    int lane = threadIdx.x & 63;
    int node = blockIdx.x * 4 + wave;
    if (node >= NN) return;
    int row = lane >> 4;       // edge slot 0..3
    int cl  = lane & 15;
    int ch  = cl * 8;
    unsigned chb = (unsigned)cl * 16u;       // byte offset of my half8 in a 512B row
    const char* xbase = (const char*)xcat;
    const float LOG2E = 1.44269504088896f;

    half8 xr8 = *(const half8*)(xbase + (size_t)node * 512 + 256 + chb);
    float4 af0 = *(const float4*)(att + ch);
    float4 af1 = *(const float4*)(att + ch + 4);
    h2v a01 = {(_Float16)(af0.x * LOG2E), (_Float16)(af0.y * LOG2E)};
    h2v a23 = {(_Float16)(af0.z * LOG2E), (_Float16)(af0.w * LOG2E)};
    h2v a45 = {(_Float16)(af1.x * LOG2E), (_Float16)(af1.y * LOG2E)};
    h2v a67 = {(_Float16)(af1.z * LOG2E), (_Float16)(af1.w * LOG2E)};
    h2v xr01 = {xr8[0], xr8[1]}, xr23 = {xr8[2], xr8[3]};
    h2v xr45 = {xr8[4], xr8[5]}, xr67 = {xr8[6], xr8[7]};
    const h2v c2 = {(_Float16)0.2f, (_Float16)0.2f};

    int k0 = off[node], k1 = off[node + 1];
    float acc0 = 0.f, acc1 = 0.f, acc2 = 0.f, acc3 = 0.f;
    float acc4 = 0.f, acc5 = 0.f, acc6 = 0.f, acc7 = 0.f, denom = 0.f;

    int rowp4 = row + 4;

    auto edge = [&](half8 cur, bool valid) {
        h2v xl01 = {cur[0], cur[1]}, xl23 = {cur[2], cur[3]};
        h2v xl45 = {cur[4], cur[5]}, xl67 = {cur[6], cur[7]};
        h2v s01 = xl01 + xr01, s23 = xl23 + xr23;
        h2v s45 = xl45 + xr45, s67 = xl67 + xr67;
        h2v l01 = hmax2v(s01, s01 * c2);
        h2v l23 = hmax2v(s23, s23 * c2);
        h2v l45 = hmax2v(s45, s45 * c2);
        h2v l67 = hmax2v(s67, s67 * c2);
        float pp = dot2f(l01, a01, dot2f(l23, a23, dot2f(l45, a45, dot2f(l67, a67, 0.f))));
        pp = sum4_all(pp);                 // per-head (quad) logit (pre-scaled by log2e)
        float wgt = valid ? ex2(pp) : 0.f;
        denom += wgt;
        acc0 = fmaf((float)cur[0], wgt, acc0);
        acc1 = fmaf((float)cur[1], wgt, acc1);
        acc2 = fmaf((float)cur[2], wgt, acc2);
        acc3 = fmaf((float)cur[3], wgt, acc3);
        acc4 = fmaf((float)cur[4], wgt, acc4);
        acc5 = fmaf((float)cur[5], wgt, acc5);
        acc6 = fmaf((float)cur[6], wgt, acc6);
        acc7 = fmaf((float)cur[7], wgt, acc7);
    };

    for (int base = k0; base < k1; base += 64) {
        int nb = min(64, k1 - base);
        int mysrc = (lane < nb) ? csr[base + lane] : 0;   // lanes>=nb give src 0: safe gather, wgt=0
        int pairs = (nb + 7) >> 3;

        auto loadpair = [&](half8& A, half8& B, int j) {
            int i0 = __shfl(mysrc, j * 8 + row, 64);
            int i1 = __shfl(mysrc, j * 8 + rowp4, 64);
            A = *(const half8*)(xbase + (((unsigned)i0 << 9) + chb));
            B = *(const half8*)(xbase + (((unsigned)i1 << 9) + chb));
        };
        auto edgepair = [&](half8 A, half8 B, int j) {
            edge(A, (j * 8 + row) < nb);
            edge(B, (j * 8 + rowp4) < nb);
        };

        half8 A0, B0, A1, B1, A2, B2;
        loadpair(A0, B0, 0);
        if (pairs > 1) loadpair(A1, B1, 1);
        if (pairs > 2) loadpair(A2, B2, 2);
        int j = 0;
        while (true) {
            edgepair(A0, B0, j); if (j + 3 < pairs) loadpair(A0, B0, j + 3); if (++j >= pairs) break;
            edgepair(A1, B1, j); if (j + 3 < pairs) loadpair(A1, B1, j + 3); if (++j >= pairs) break;
            edgepair(A2, B2, j); if (j + 3 < pairs) loadpair(A2, B2, j + 3); if (++j >= pairs) break;
        }
    }
    // combine the 4 edge slots
    acc0 += __shfl_xor(acc0, 16, 64); acc0 += __shfl_xor(acc0, 32, 64);
    acc1 += __shfl_xor(acc1, 16, 64); acc1 += __shfl_xor(acc1, 32, 64);
    acc2 += __shfl_xor(acc2, 16, 64); acc2 += __shfl_xor(acc2, 32, 64);
    acc3 += __shfl_xor(acc3, 16, 64); acc3 += __shfl_xor(acc3, 32, 64);
    acc4 += __shfl_xor(acc4, 16, 64); acc4 += __shfl_xor(acc4, 32, 64);
    acc5 += __shfl_xor(acc5, 16, 64); acc5 += __shfl_xor(acc5, 32, 64);
    acc6 += __shfl_xor(acc6, 16, 64); acc6 += __shfl_xor(acc6, 32, 64);
    acc7 += __shfl_xor(acc7, 16, 64); acc7 += __shfl_xor(acc7, 32, 64);
    denom += __shfl_xor(denom, 16, 64); denom += __shfl_xor(denom, 32, 64);
    if (row == 0) {
        float inv = 1.f / (denom + 1e-16f);
        float4 s0 = *(const float4*)(scb + ch), s1 = *(const float4*)(scb + ch + 4);
        float4 h0 = *(const float4*)(shb + ch), h1f = *(const float4*)(shb + ch + 4);
        float o[8];
        o[0] = elu_f(fmaf(acc0 * inv, s0.x, h0.x));
        o[1] = elu_f(fmaf(acc1 * inv, s0.y, h0.y));
        o[2] = elu_f(fmaf(acc2 * inv, s0.z, h0.z));
        o[3] = elu_f(fmaf(acc3 * inv, s0.w, h0.w));
        o[4] = elu_f(fmaf(acc4 * inv, s1.x, h1f.x));
        o[5] = elu_f(fmaf(acc5 * inv, s1.y, h1f.y));
        o[6] = elu_f(fmaf(acc6 * inv, s1.z, h1f.z));
        o[7] = elu_f(fmaf(acc7 * inv, s1.w, h1f.w));
        half8 oh = {(_Float16)o[0], (_Float16)o[1], (_Float16)o[2], (_Float16)o[3],
                    (_Float16)o[4], (_Float16)o[5], (_Float16)o[6], (_Float16)o[7]};
        *(half8*)(h1 + (size_t)node * 128 + ch) = oh;
    }
}

// ================= fused GATv2 layer 2: 8 edges/iter x 8 lanes x 4ch =================
// xcat2 [N][64] fp16 (xl 0..31, xr 32..63). row=lane>>3 = edge slot, cl=lane&7, ch=4*cl.
// 3-pair pipeline (pair = 16 edges), att pre-scaled by log2e, BN pre-folded.
__global__ __launch_bounds__(256) void fused_gat2(
    const int* __restrict__ off, const int* __restrict__ csr,
    const __half* __restrict__ xcat2, const float* __restrict__ att,
    const float* __restrict__ scb, const float* __restrict__ shb,
    __half* __restrict__ h2)
{
    int wave = threadIdx.x >> 6;
    int lane = threadIdx.x & 63;
    int node = blockIdx.x * 4 + wave;
    if (node >= NN) return;
    int row = lane >> 3;       // edge slot 0..7
    int cl  = lane & 7;
    int ch  = cl * 4;
    unsigned chb = (unsigned)cl * 8u;        // byte offset of my h4v in a 128B row
    const char* xbase = (const char*)xcat2;
    const float LOG2E = 1.44269504088896f;

    h4v xr4 = *(const h4v*)(xbase + (size_t)node * 128 + 64 + chb);
    h2v xr01 = {xr4[0], xr4[1]}, xr23 = {xr4[2], xr4[3]};
    float4 af = *(const float4*)(att + ch);
    h2v a01 = {(_Float16)(af.x * LOG2E), (_Float16)(af.y * LOG2E)};
    h2v a23 = {(_Float16)(af.z * LOG2E), (_Float16)(af.w * LOG2E)};
    const h2v c2 = {(_Float16)0.2f, (_Float16)0.2f};

    int k0 = off[node], k1 = off[node + 1];
    float acc0 = 0.f, acc1 = 0.f, acc2 = 0.f, acc3 = 0.f, denom = 0.f;

    int rowp8 = row + 8;

    auto edge = [&](h4v cur, bool valid) {
        h2v xl01 = {cur[0], cur[1]}, xl23 = {cur[2], cur[3]};
        h2v s01 = xl01 + xr01, s23 = xl23 + xr23;
        h2v l01 = hmax2v(s01, s01 * c2);
        h2v l23 = hmax2v(s23, s23 * c2);
        float pp = dot2f(l01, a01, dot2f(l23, a23, 0.f));
        pp = sum8_all(pp);                 // per-edge 32-ch logit (pre-scaled by log2e)
        float wgt = valid ? ex2(pp) : 0.f;
        denom += wgt;
        acc0 = fmaf((float)cur[0], wgt, acc0);
        acc1 = fmaf((float)cur[1], wgt, acc1);
        acc2 = fmaf((float)cur[2], wgt, acc2);
        acc3 = fmaf((float)cur[3], wgt, acc3);
    };

    for (int base = k0; base < k1; base += 64) {
        int nb = min(64, k1 - base);
        int mysrc = (lane < nb) ? csr[base + lane] : 0;
        int pairs = (nb + 15) >> 4;

        auto loadpair = [&](h4v& A, h4v& B, int j) {
            int i0 = __shfl(mysrc, j * 16 + row, 64);
            int i1 = __shfl(mysrc, j * 16 + rowp8, 64);
            A = *(const h4v*)(xbase + (((unsigned)i0 << 7) + chb));
            B = *(const h4v*)(xbase + (((unsigned)i1 << 7) + chb));
        };
        auto edgepair = [&](h4v A, h4v B, int j) {
            edge(A, (j * 16 + row) < nb);
            edge(B, (j * 16 + rowp8) < nb);
        };

        h4v A0, B0, A1, B1, A2, B2;
        loadpair(A0, B0, 0);
        if (pairs > 1) loadpair(A1, B1, 1);
        if (pairs > 2) loadpair(A2, B2, 2);
        int j = 0;
        while (true) {
            edgepair(A0, B0, j); if (j + 3 < pairs) loadpair(A0, B0, j + 3); if (++j >= pairs) break;
            edgepair(A1, B1, j); if (j + 3 < pairs) loadpair(A1, B1, j + 3); if (++j >= pairs) break;
            edgepair(A2, B2, j); if (j + 3 < pairs) loadpair(A2, B2, j + 3); if (++j >= pairs) break;
        }
    }
    // combine the 8 edge slots
    acc0 += __shfl_xor(acc0, 8, 64); acc0 += __shfl_xor(acc0, 16, 64); acc0 += __shfl_xor(acc0, 32, 64);
    acc1 += __shfl_xor(acc1, 8, 64); acc1 += __shfl_xor(acc1, 16, 64); acc1 += __shfl_xor(acc1, 32, 64);
    acc2 += __shfl_xor(acc2, 8, 64); acc2 += __shfl_xor(acc2, 16, 64); acc2 += __shfl_xor(acc2, 32, 64);
    acc3 += __shfl_xor(acc3, 8, 64); acc3 += __shfl_xor(acc3, 16, 64); acc3 += __shfl_xor(acc3, 32, 64);
    denom += __shfl_xor(denom, 8, 64); denom += __shfl_xor(denom, 16, 64); denom += __shfl_xor(denom, 32, 64);
    if (row == 0) {
        float inv = 1.f / (denom + 1e-16f);
        float4 sv = *(const float4*)(scb + ch);
        float4 hv = *(const float4*)(shb + ch);
        float o0 = elu_f(fmaf(acc0 * inv, sv.x, hv.x));
        float o1 = elu_f(fmaf(acc1 * inv, sv.y, hv.y));
        float o2 = elu_f(fmaf(acc2 * inv, sv.z, hv.z));
        float o3 = elu_f(fmaf(acc3 * inv, sv.w, hv.w));
        h4v oh = {(_Float16)o0, (_Float16)o1, (_Float16)o2, (_Float16)o3};
        *(h4v*)(h2 + (size_t)node * 32 + ch) = oh;
    }
}

extern "C" void kernel_launch(void* const* d_in, const int* in_sizes, int n_in,
                              void* d_out, int out_size, void* d_ws, size_t ws_size,
                              hipStream_t stream)
{
    const float* x_pca = (const float*)d_in[0];
    const float* x_bio = (const float*)d_in[1];
    const int*   ei    = (const int*)d_in[2];
    const float* bioW1 = (const float*)d_in[3];
    const float* biob1 = (const float*)d_in[4];
    const float* bn0_g = (const float*)d_in[5];
    const float* bn0_b = (const float*)d_in[6];
    const float* bn0_m = (const float*)d_in[7];
    const float* bn0_v = (const float*)d_in[8];
    const float* bioW2 = (const float*)d_in[9];
    const float* biob2 = (const float*)d_in[10];
    const float* Wl1   = (const float*)d_in[11];
    const float* bl1   = (const float*)d_in[12];
    const float* Wr1   = (const float*)d_in[13];
    const float* br1   = (const float*)d_in[14];
    const float* att1  = (const float*)d_in[15];
    const float* bias1 = (const float*)d_in[16];
    const float* bn1_g = (const float*)d_in[17];
    const float* bn1_b = (const float*)d_in[18];
    const float* bn1_m = (const float*)d_in[19];
    const float* bn1_v = (const float*)d_in[20];
    const float* Wl2   = (const float*)d_in[21];
    const float* bl2   = (const float*)d_in[22];
    const float* Wr2   = (const float*)d_in[23];
    const float* br2   = (const float*)d_in[24];
    const float* att2  = (const float*)d_in[25];
    const float* bias2 = (const float*)d_in[26];
    const float* bn2_g = (const float*)d_in[27];
    const float* bn2_b = (const float*)d_in[28];
    const float* bn2_m = (const float*)d_in[29];
    const float* bn2_v = (const float*)d_in[30];
    const float* predW = (const float*)d_in[31];
    const float* predb = (const float*)d_in[32];

    float* ws = (float*)d_ws;
    __half* xh    = (__half*)ws;                       // N*96 halves
    float*  p0    = ws + 4800000;
    __half* xcat1 = (__half*)p0;                       // N*256 halves
    float*  p1    = p0 + 12800000;
    __half* h1h   = (__half*)p1;                       // N*128 halves
    float*  p2    = p1 + 6400000;
    __half* xcat2 = (__half*)p2;                       // N*64 halves
    float*  p3    = p2 + 3200000;
    __half* h2h   = (__half*)p3;                       // N*32 halves
    float*  p4    = p3 + 1600000;
    __half* wcat1 = (__half*)p4;                       // 256*96 h
    float*  bcat1 = p4 + 12288;                        // 256
    __half* wcat2 = (__half*)(bcat1 + 256);            // 64*128 h
    float*  bcat2 = bcat1 + 256 + 4096;                // 64
    __half* wpred = (__half*)(bcat2 + 64);             // 64*32 h
    float*  bpred = bcat2 + 64 + 1024;                 // 64
    float*  scb1  = bpred + 64;                        // 128
    float*  shb1  = scb1 + 128;                        // 128
    float*  scb2  = shb1 + 128;                        // 32
    float*  shb2  = scb2 + 32;                         // 32
    int*    ib    = (int*)(shb2 + 32);
    unsigned* ebuf = (unsigned*)ib;                    // NEP
    int*    hist   = ib + NEP;                         // HISTN
    int*    part   = hist + HISTN;                     // 128
    int*    off    = part + 128;                       // NN+1
    int*    csr    = off + NN + 1;                     // NEP

    float* out = (float*)d_out;

    // ---- CSR build (deterministic radix partition) ----
    part_hist<<<NBLK, 256, 0, stream>>>(ei, hist);
    scan_p1<<<HSCAN_BLOCKS, 256, 0, stream>>>(hist, part, HISTN);
    scan_p2<<<1, 128, 0, stream>>>(part, HSCAN_BLOCKS, off);
    scan_p3<<<HSCAN_BLOCKS, 256, 0, stream>>>(hist, part, HISTN);
    part_scatter<<<NBLK, 256, 0, stream>>>(ei, hist, ebuf);
    bucket_csr<<<NBUCK2, 256, 0, stream>>>(hist, ebuf, off, csr);

    // ---- node features (fp16, pca+bio+pad fused) ----
    bio_kernel<<<(NN + 255) / 256, 256, 0, stream>>>(
        x_bio, x_pca, bioW1, biob1, bn0_g, bn0_b, bn0_m, bn0_v, bioW2, biob2, xh);

    // ---- all weight conversions + BN pre-fold ----
    wconvert_all<<<139, 256, 0, stream>>>(
        Wl1, Wr1, bl1, br1, Wl2, Wr2, bl2, br2, predW, predb,
        bias1, bn1_g, bn1_b, bn1_m, bn1_v,
        bias2, bn2_g, bn2_b, bn2_m, bn2_v,
        wcat1, bcat1, wcat2, bcat2, wpred, bpred,
        scb1, shb1, scb2, shb2);

    // ---- layer-1 transform ----
    mfma_gemm<3, 256, false><<<(NN + 63) / 64, 256, 0, stream>>>(xh, wcat1, bcat1, xcat1, NN, 0);

    // ---- fused layer-1 edge phase ----
    fused_gat1<<<(NN + 3) / 4, 256, 0, stream>>>(
        off, csr, xcat1, att1, scb1, shb1, h1h);

    // ---- layer-2 transform ----
    mfma_gemm<4, 64, false><<<(NN + 63) / 64, 256, 0, stream>>>(h1h, wcat2, bcat2, xcat2, NN, 0);

    // ---- fused layer-2 edge phase ----
    fused_gat2<<<(NN + 3) / 4, 256, 0, stream>>>(
        off, csr, xcat2, att2, scb2, shb2, h2h);

    // ---- prediction head (MFMA, fp32 out) ----
    mfma_gemm<1, 64, true><<<(NN + 63) / 64, 256, 0, stream>>>(h2h, wpred, bpred, out, NN, 50);
}

// Round 3
// 399.395 us; speedup vs baseline: 1.0347x; 1.0347x over previous
//
#include <hip/hip_runtime.h>
#include <hip/hip_fp16.h>
#include <cstdint>
#include <cstddef>

#define NN 100000
#define NE 1600000
#define NEP (NE + NN)              // 1,700,000
#define NBLK 200                   // partition blocks
#define CHUNK ((NEP + NBLK - 1) / NBLK)   // 8500
#define NBUCK2 ((NN + 255) / 256)  // 391 buckets of 256 dst nodes
#define HISTN (NBUCK2 * NBLK)      // 78,200
#define HSCAN_BLOCKS ((HISTN + 1023) / 1024)  // 77

typedef __attribute__((ext_vector_type(8))) _Float16 half8;
typedef __attribute__((ext_vector_type(4))) _Float16 h4v;
typedef __attribute__((ext_vector_type(2))) _Float16 h2v;
typedef __attribute__((ext_vector_type(4))) float float4v;

__device__ __forceinline__ float elu_f(float x) {
    return x > 0.f ? x : __expf(x) - 1.f;
}

__device__ __forceinline__ float ex2(float x) {
#if __has_builtin(__builtin_amdgcn_exp2f)
    return __builtin_amdgcn_exp2f(x);
#else
    return exp2f(x);
#endif
}

// ---- DPP reduce helpers (pure VALU) ----
template<int CTRL>
__device__ __forceinline__ float dpp_add(float x) {
    int s = __builtin_amdgcn_update_dpp(0, __float_as_int(x), CTRL, 0xF, 0xF, true);
    return x + __int_as_float(s);
}
// allsum within aligned 4-lane quads (one GAT1 head = 4 lanes x 8ch)
__device__ __forceinline__ float sum4_all(float x) {
    x = dpp_add<0xB1>(x); x = dpp_add<0x4E>(x);
    return x;
}
// allsum within aligned 8-lane groups (one GAT2 edge = 8 lanes x 4ch)
__device__ __forceinline__ float sum8_all(float x) {
    x = dpp_add<0xB1>(x); x = dpp_add<0x4E>(x); x = dpp_add<0x141>(x);
    return x;
}

__device__ __forceinline__ float dot2f(h2v a, h2v b, float c) {
#if __has_builtin(__builtin_amdgcn_fdot2)
    return __builtin_amdgcn_fdot2(a, b, c, false);
#else
    return fmaf((float)a[0], (float)b[0], fmaf((float)a[1], (float)b[1], c));
#endif
}

__device__ __forceinline__ h2v hmax2v(h2v a, h2v b) {
#if __has_builtin(__builtin_elementwise_max)
    return __builtin_elementwise_max(a, b);
#else
    __half2 r = __hmax2(*(__half2*)&a, *(__half2*)&b);
    return *(h2v*)&r;
#endif
}

// ================= CSR build: deterministic radix partition =================

__global__ __launch_bounds__(256) void part_hist(const int* __restrict__ ei, int* __restrict__ hist)
{
    __shared__ int cnt[NBUCK2];
    int tid = threadIdx.x, k = blockIdx.x;
    for (int i = tid; i < NBUCK2; i += 256) cnt[i] = 0;
    __syncthreads();
    int e0 = k * CHUNK, e1 = min(e0 + CHUNK, NEP);
    for (int e = e0 + tid; e < e1; e += 256) {
        int dst = (e < NE) ? ei[NE + e] : e - NE;
        atomicAdd(&cnt[dst >> 8], 1);
    }
    __syncthreads();
    for (int i = tid; i < NBUCK2; i += 256) hist[i * NBLK + k] = cnt[i];
}

__global__ __launch_bounds__(256) void scan_p1(const int* __restrict__ src, int* __restrict__ part, int n)
{
    __shared__ int wsum[4];
    int t = threadIdx.x;
    int i0 = blockIdx.x * 1024 + t * 4;
    int s = 0;
    if (i0 + 3 < n) { int4 d = *(const int4*)(src + i0); s = d.x + d.y + d.z + d.w; }
    else { for (int k = 0; k < 4; k++) if (i0 + k < n) s += src[i0 + k]; }
    for (int d = 1; d < 64; d <<= 1) s += __shfl_xor(s, d, 64);
    if ((t & 63) == 0) wsum[t >> 6] = s;
    __syncthreads();
    if (t == 0) part[blockIdx.x] = wsum[0] + wsum[1] + wsum[2] + wsum[3];
}

__global__ __launch_bounds__(128) void scan_p2(int* __restrict__ part, int nb, int* __restrict__ off)
{
    __shared__ int wt[2];
    int t = threadIdx.x;
    int lane = t & 63, w = t >> 6;
    int v = (t < nb) ? part[t] : 0;
    int x = v;
    for (int d = 1; d < 64; d <<= 1) { int y = __shfl_up(x, d, 64); if (lane >= d) x += y; }
    if (lane == 63) wt[w] = x;
    __syncthreads();
    int base = (w == 1) ? wt[0] : 0;
    int excl = base + x - v;
    if (t < nb) part[t] = excl;
    if (t == 0) off[NN] = NEP;
}

__global__ __launch_bounds__(256) void scan_p3(int* __restrict__ data, const int* __restrict__ part, int n)
{
    __shared__ int wsum[4];
    int t = threadIdx.x, lane = t & 63, w = t >> 6;
    int i0 = blockIdx.x * 1024 + t * 4;
    int d0 = 0, d1 = 0, d2 = 0, d3 = 0;
    if (i0 + 3 < n) { int4 d = *(const int4*)(data + i0); d0 = d.x; d1 = d.y; d2 = d.z; d3 = d.w; }
    else if (i0 < n) {
        d0 = data[i0];
        if (i0 + 1 < n) d1 = data[i0 + 1];
        if (i0 + 2 < n) d2 = data[i0 + 2];
    }
    int s = d0 + d1 + d2 + d3;
    int x = s;
    for (int d = 1; d < 64; d <<= 1) { int y = __shfl_up(x, d, 64); if (lane >= d) x += y; }
    if (lane == 63) wsum[w] = x;
    __syncthreads();
    int wb = 0;
    for (int i = 0; i < w; i++) wb += wsum[i];
    int base = part[blockIdx.x] + wb + x - s;
    if (i0 < n)     data[i0]     = base;
    if (i0 + 1 < n) data[i0 + 1] = base + d0;
    if (i0 + 2 < n) data[i0 + 2] = base + d0 + d1;
    if (i0 + 3 < n) data[i0 + 3] = base + d0 + d1 + d2;
}

__global__ __launch_bounds__(256) void part_scatter(const int* __restrict__ ei,
                                                    const int* __restrict__ hist,
                                                    unsigned* __restrict__ ebuf)
{
    __shared__ int cur[NBUCK2];
    int tid = threadIdx.x, k = blockIdx.x;
    for (int i = tid; i < NBUCK2; i += 256) cur[i] = hist[i * NBLK + k];
    __syncthreads();
    int e0 = k * CHUNK, e1 = min(e0 + CHUNK, NEP);
    for (int e = e0 + tid; e < e1; e += 256) {
        int src, dst;
        if (e < NE) { src = ei[e]; dst = ei[NE + e]; } else { src = dst = e - NE; }
        int pos = atomicAdd(&cur[dst >> 8], 1);
        ebuf[pos] = (unsigned)src | ((unsigned)(dst & 255) << 24);
    }
}

__global__ __launch_bounds__(256) void bucket_csr(const int* __restrict__ hist,
                                                  const unsigned* __restrict__ ebuf,
                                                  int* __restrict__ off, int* __restrict__ csr)
{
    __shared__ int cnt[256];
    __shared__ int cur[256];
    __shared__ int wsum[4];
    int b = blockIdx.x;
    int d0 = b << 8;
    int tid = threadIdx.x;
    int e0 = hist[b * NBLK];
    int e1 = (b + 1 < NBUCK2) ? hist[(b + 1) * NBLK] : NEP;
    cnt[tid] = 0;
    __syncthreads();
    for (int i = e0 + tid; i < e1; i += 256) atomicAdd(&cnt[ebuf[i] >> 24], 1);
    __syncthreads();
    int c = cnt[tid];
    int x = c;
    int lane = tid & 63, w = tid >> 6;
    for (int d = 1; d < 64; d <<= 1) { int y = __shfl_up(x, d, 64); if (lane >= d) x += y; }
    if (lane == 63) wsum[w] = x;
    __syncthreads();
    int wb = 0;
    for (int i = 0; i < w; i++) wb += wsum[i];
    int excl = wb + x - c;
    cur[tid] = e0 + excl;
    int node = d0 + tid;
    if (node < NN) off[node] = e0 + excl;
    __syncthreads();
    for (int i = e0 + tid; i < e1; i += 256) {
        unsigned v = ebuf[i];
        int p = atomicAdd(&cur[v >> 24], 1);
        csr[p] = (int)(v & 0xFFFFFF);
    }
}

// ================= node feature prep (fp16 x [N][96]; bio + pca + pad fused) =================

__global__ __launch_bounds__(256) void bio_kernel(
    const float* __restrict__ xb, const float* __restrict__ xp,
    const float* __restrict__ W1, const float* __restrict__ b1,
    const float* __restrict__ g0, const float* __restrict__ bb0,
    const float* __restrict__ m0, const float* __restrict__ v0,
    const float* __restrict__ W2, const float* __restrict__ b2,
    __half* __restrict__ xh)
{
    __shared__ float sW1[16*64], sW2[16*16], sb1[16], sb2[16], ss[16], st[16];
    int tid = threadIdx.x;
    for (int idx = tid; idx < 1024; idx += 256) sW1[idx] = W1[idx];
    if (tid < 256) sW2[tid] = W2[tid];
    if (tid < 16) {
        sb1[tid] = b1[tid]; sb2[tid] = b2[tid];
        float s = g0[tid] * rsqrtf(v0[tid] + 1e-5f);
        ss[tid] = s; st[tid] = bb0[tid] - m0[tid] * s;
    }
    __syncthreads();
    int i = blockIdx.x * 256 + tid;
    if (i >= NN) return;
    float bio[64];
    const float4* p = (const float4*)(xb + (size_t)i * 64);
    #pragma unroll
    for (int q = 0; q < 16; q++) {
        float4 f = p[q];
        bio[q*4] = f.x; bio[q*4+1] = f.y; bio[q*4+2] = f.z; bio[q*4+3] = f.w;
    }
    float t1[16];
    #pragma unroll
    for (int j = 0; j < 16; j++) {
        float acc = sb1[j];
        #pragma unroll
        for (int k = 0; k < 64; k++) acc += bio[k] * sW1[j*64 + k];
        acc = acc * ss[j] + st[j];
        t1[j] = elu_f(acc);
    }
    __half* xrow = xh + (size_t)i * 96;
    const float* xpr = xp + (size_t)i * 50;
    #pragma unroll
    for (int j = 0; j < 25; j++) {
        float2 f = *(const float2*)(xpr + 2 * j);
        *(__half2*)(xrow + 2 * j) = __floats2half2_rn(f.x, f.y);
    }
    #pragma unroll
    for (int j = 0; j < 16; j++) {
        float acc = sb2[j];
        #pragma unroll
        for (int k = 0; k < 16; k++) acc += t1[k] * sW2[j*16 + k];
        xrow[50 + j] = __float2half(elu_f(acc));
    }
    __half2 z2 = __floats2half2_rn(0.f, 0.f);
    #pragma unroll
    for (int j = 0; j < 15; j++) *(__half2*)(xrow + 66 + 2 * j) = z2;
}

// ================= all weight conversions + BN/bias pre-fold in one launch =================

__global__ __launch_bounds__(256) void wconvert_all(
    const float* __restrict__ Wl1, const float* __restrict__ Wr1,
    const float* __restrict__ bl1, const float* __restrict__ br1,
    const float* __restrict__ Wl2, const float* __restrict__ Wr2,
    const float* __restrict__ bl2, const float* __restrict__ br2,
    const float* __restrict__ predW, const float* __restrict__ predb,
    const float* __restrict__ bias1, const float* __restrict__ bn1g,
    const float* __restrict__ bn1b, const float* __restrict__ bn1m,
    const float* __restrict__ bn1v,
    const float* __restrict__ bias2, const float* __restrict__ bn2g,
    const float* __restrict__ bn2b, const float* __restrict__ bn2m,
    const float* __restrict__ bn2v,
    __half* __restrict__ wcat1, float* __restrict__ bcat1,
    __half* __restrict__ wcat2, float* __restrict__ bcat2,
    __half* __restrict__ wpred, float* __restrict__ bpred,
    float* __restrict__ scb1, float* __restrict__ shb1,
    float* __restrict__ scb2, float* __restrict__ shb2)
{
    int t = blockIdx.x * 256 + threadIdx.x;
    if (t < 256 * 96) {
        int j = t / 96, k = t - j * 96;
        float v = (k < 66) ? ((j < 128) ? Wl1[j * 66 + k] : Wr1[(j - 128) * 66 + k]) : 0.f;
        wcat1[t] = __float2half(v);
    }
    int u = t - 256 * 96;
    if (u >= 0 && u < 64 * 128) {
        int j = u >> 7, k = u & 127;
        float v = (j < 32) ? Wl2[j * 128 + k] : Wr2[(j - 32) * 128 + k];
        wcat2[u] = __float2half(v);
    }
    int w = u - 64 * 128;
    if (w >= 0 && w < 64 * 32) {
        int j = w >> 5;
        wpred[w] = __float2half(j < 50 ? predW[w] : 0.f);
    }
    int z = w - 64 * 32;
    if (z >= 0 && z < 256) bcat1[z] = (z < 128) ? bl1[z] : br1[z - 128];
    int z2 = z - 256;
    if (z2 >= 0 && z2 < 64) bcat2[z2] = (z2 < 32) ? bl2[z2] : br2[z2 - 32];
    int z3 = z2 - 64;
    if (z3 >= 0 && z3 < 64) bpred[z3] = (z3 < 50) ? predb[z3] : 0.f;
    int z4 = z3 - 64;
    if (z4 >= 0 && z4 < 128) {
        float sc = bn1g[z4] * rsqrtf(bn1v[z4] + 1e-5f);
        scb1[z4] = sc;
        shb1[z4] = bn1b[z4] + (bias1[z4] - bn1m[z4]) * sc;
    }
    int z5 = z4 - 128;
    if (z5 >= 0 && z5 < 32) {
        float sc = bn2g[z5] * rsqrtf(bn2v[z5] + 1e-5f);
        scb2[z5] = sc;
        shb2[z5] = bn2b[z5] + (bias2[z5] - bn2m[z5]) * sc;
    }
}

// ================= MFMA f16 GEMM (split output: col<NSPL -> out1, else out2) =================
template<int KT, int NC, int NSPL, bool FOUT>
__global__ __launch_bounds__(256) void mfma_gemm(
    const __half* __restrict__ in, const __half* __restrict__ wcat,
    const float* __restrict__ bcat, void* __restrict__ outv, void* __restrict__ outv2,
    int n, int ncol)
{
    constexpr int K = KT * 32;
    constexpr int KP = K + 8;
    __shared__ __half sW[NC * KP];
    __shared__ __half sX[64 * KP];
    __shared__ float sB[NC];
    int tid = threadIdx.x;
    for (int idx = tid * 8; idx < NC * K; idx += 256 * 8) {
        int r = idx / K, c = idx - r * K;
        *(half8*)(&sW[r * KP + c]) = *(const half8*)(&wcat[r * K + c]);
    }
    for (int idx = tid; idx < NC; idx += 256) sB[idx] = bcat[idx];
    int row0 = blockIdx.x * 64;
    half8 hz = {0, 0, 0, 0, 0, 0, 0, 0};
    for (int idx = tid * 8; idx < 64 * K; idx += 256 * 8) {
        int r = idx / K, c = idx - r * K;
        int gr = row0 + r;
        half8 v = (gr < n) ? *(const half8*)(&in[(size_t)gr * K + c]) : hz;
        *(half8*)(&sX[r * KP + c]) = v;
    }
    __syncthreads();
    int w = tid >> 6, lane = tid & 63;
    int m = lane & 15, quad = lane >> 4;
    half8 a[KT];
    #pragma unroll
    for (int kt = 0; kt < KT; kt++)
        a[kt] = *(const half8*)(&sX[(w * 16 + m) * KP + kt * 32 + quad * 8]);
    #pragma unroll 1
    for (int nt = 0; nt < NC / 16; nt++) {
        float4v acc = {0.f, 0.f, 0.f, 0.f};
        #pragma unroll
        for (int kt = 0; kt < KT; kt++) {
            half8 bfrag = *(const half8*)(&sW[(nt * 16 + m) * KP + kt * 32 + quad * 8]);
            acc = __builtin_amdgcn_mfma_f32_16x16x32_f16(a[kt], bfrag, acc, 0, 0, 0);
        }
        int col = nt * 16 + m;
        float bias = sB[col];
        #pragma unroll
        for (int i = 0; i < 4; i++) {
            int r = row0 + w * 16 + quad * 4 + i;
            if (r < n) {
                if (FOUT) { if (col < ncol) ((float*)outv)[(size_t)r * ncol + col] = acc[i] + bias; }
                else if (col < NSPL)
                    ((__half*)outv)[(size_t)r * NSPL + col] = __float2half(acc[i] + bias);
                else
                    ((__half*)outv2)[(size_t)r * (NC - NSPL) + (col - NSPL)] = __float2half(acc[i] + bias);
            }
        }
    }
}

// ================= fused GATv2 layer 1: 4 edges/iter x 16 lanes x 8ch =================
// xl [N][128] fp16 (dense gather array), xr [N][128] fp16 (streamed once/node).
// row=lane>>4 = edge slot, cl=lane&15, ch=8*cl. Head = 32 ch = 4 lanes -> sum4_all.
// Depth-2 prefetch (R1 structure). att pre-scaled by log2(e): wgt = exp2(pp).
// BN+bias pre-folded: o = elu(acc*inv*sc + sh).
__global__ __launch_bounds__(256) void fused_gat1(
    const int* __restrict__ off, const int* __restrict__ csr,
    const __half* __restrict__ xl, const __half* __restrict__ xr,
    const float* __restrict__ att,
    const float* __restrict__ scb, const float* __restrict__ shb,
    __half* __restrict__ h1)
{
    int wave = threadIdx.x >> 6;
    int lane = threadIdx.x & 63;
    int node = blockIdx.x * 4 + wave;
    if (node >= NN) return;
    int row = lane >> 4;       // edge slot 0..3
    int cl  = lane & 15;
    int ch  = cl * 8;
    unsigned chb = (unsigned)cl * 16u;       // byte offset of my half8 in a 256B row
    const char* xbase = (const char*)xl;
    const float LOG2E = 1.44269504088896f;

    half8 xr8 = *(const half8*)((const char*)xr + (size_t)node * 256 + chb);
    float4 af0 = *(const float4*)(att + ch);
    float4 af1 = *(const float4*)(att + ch + 4);
    h2v a01 = {(_Float16)(af0.x * LOG2E), (_Float16)(af0.y * LOG2E)};
    h2v a23 = {(_Float16)(af0.z * LOG2E), (_Float16)(af0.w * LOG2E)};
    h2v a45 = {(_Float16)(af1.x * LOG2E), (_Float16)(af1.y * LOG2E)};
    h2v a67 = {(_Float16)(af1.z * LOG2E), (_Float16)(af1.w * LOG2E)};
    h2v xr01 = {xr8[0], xr8[1]}, xr23 = {xr8[2], xr8[3]};
    h2v xr45 = {xr8[4], xr8[5]}, xr67 = {xr8[6], xr8[7]};
    const h2v c2 = {(_Float16)0.2f, (_Float16)0.2f};

    int k0 = off[node], k1 = off[node + 1];
    float acc0 = 0.f, acc1 = 0.f, acc2 = 0.f, acc3 = 0.f;
    float acc4 = 0.f, acc5 = 0.f, acc6 = 0.f, acc7 = 0.f, denom = 0.f;

    int rowp4  = row + 4;
    int rowp8  = row + 8;
    int rowp12 = row + 12;

    auto edge = [&](half8 cur, bool valid) {
        h2v xl01 = {cur[0], cur[1]}, xl23 = {cur[2], cur[3]};
        h2v xl45 = {cur[4], cur[5]}, xl67 = {cur[6], cur[7]};
        h2v s01 = xl01 + xr01, s23 = xl23 + xr23;
        h2v s45 = xl45 + xr45, s67 = xl67 + xr67;
        h2v l01 = hmax2v(s01, s01 * c2);
        h2v l23 = hmax2v(s23, s23 * c2);
        h2v l45 = hmax2v(s45, s45 * c2);
        h2v l67 = hmax2v(s67, s67 * c2);
        float pp = dot2f(l01, a01, dot2f(l23, a23, dot2f(l45, a45, dot2f(l67, a67, 0.f))));
        pp = sum4_all(pp);                 // per-head (quad) logit (pre-scaled by log2e)
        float wgt = valid ? ex2(pp) : 0.f;
        denom += wgt;
        acc0 = fmaf((float)cur[0], wgt, acc0);
        acc1 = fmaf((float)cur[1], wgt, acc1);
        acc2 = fmaf((float)cur[2], wgt, acc2);
        acc3 = fmaf((float)cur[3], wgt, acc3);
        acc4 = fmaf((float)cur[4], wgt, acc4);
        acc5 = fmaf((float)cur[5], wgt, acc5);
        acc6 = fmaf((float)cur[6], wgt, acc6);
        acc7 = fmaf((float)cur[7], wgt, acc7);
    };

    for (int base = k0; base < k1; base += 64) {
        int nb = min(64, k1 - base);
        int mysrc = (lane < nb) ? csr[base + lane] : 0;
        int nbm1 = nb - 1;
        int i0 = __shfl(mysrc, min(row, nbm1), 64);
        int i1 = __shfl(mysrc, min(rowp4, nbm1), 64);
        half8 c0 = *(const half8*)(xbase + (((unsigned)i0 << 8) + chb));
        half8 c1 = *(const half8*)(xbase + (((unsigned)i1 << 8) + chb));
        for (int t = 0; t < nb; t += 8) {
            int i2 = __shfl(mysrc, min(t + rowp8, nbm1), 64);
            int i3 = __shfl(mysrc, min(t + rowp12, nbm1), 64);
            half8 cc2 = *(const half8*)(xbase + (((unsigned)i2 << 8) + chb));
            half8 cc3 = *(const half8*)(xbase + (((unsigned)i3 << 8) + chb));
            edge(c0, (t + row) < nb);
            edge(c1, (t + rowp4) < nb);
            c0 = cc2; c1 = cc3;
        }
    }
    // combine the 4 edge slots
    acc0 += __shfl_xor(acc0, 16, 64); acc0 += __shfl_xor(acc0, 32, 64);
    acc1 += __shfl_xor(acc1, 16, 64); acc1 += __shfl_xor(acc1, 32, 64);
    acc2 += __shfl_xor(acc2, 16, 64); acc2 += __shfl_xor(acc2, 32, 64);
    acc3 += __shfl_xor(acc3, 16, 64); acc3 += __shfl_xor(acc3, 32, 64);
    acc4 += __shfl_xor(acc4, 16, 64); acc4 += __shfl_xor(acc4, 32, 64);
    acc5 += __shfl_xor(acc5, 16, 64); acc5 += __shfl_xor(acc5, 32, 64);
    acc6 += __shfl_xor(acc6, 16, 64); acc6 += __shfl_xor(acc6, 32, 64);
    acc7 += __shfl_xor(acc7, 16, 64); acc7 += __shfl_xor(acc7, 32, 64);
    denom += __shfl_xor(denom, 16, 64); denom += __shfl_xor(denom, 32, 64);
    if (row == 0) {
        float inv = 1.f / (denom + 1e-16f);
        float4 s0 = *(const float4*)(scb + ch), s1 = *(const float4*)(scb + ch + 4);
        float4 h0 = *(const float4*)(shb + ch), h1f = *(const float4*)(shb + ch + 4);
        float o[8];
        o[0] = elu_f(fmaf(acc0 * inv, s0.x, h0.x));
        o[1] = elu_f(fmaf(acc1 * inv, s0.y, h0.y));
        o[2] = elu_f(fmaf(acc2 * inv, s0.z, h0.z));
        o[3] = elu_f(fmaf(acc3 * inv, s0.w, h0.w));
        o[4] = elu_f(fmaf(acc4 * inv, s1.x, h1f.x));
        o[5] = elu_f(fmaf(acc5 * inv, s1.y, h1f.y));
        o[6] = elu_f(fmaf(acc6 * inv, s1.z, h1f.z));
        o[7] = elu_f(fmaf(acc7 * inv, s1.w, h1f.w));
        half8 oh = {(_Float16)o[0], (_Float16)o[1], (_Float16)o[2], (_Float16)o[3],
                    (_Float16)o[4], (_Float16)o[5], (_Float16)o[6], (_Float16)o[7]};
        *(half8*)(h1 + (size_t)node * 128 + ch) = oh;
    }
}

// ================= fused GATv2 layer 2: 8 edges/iter x 8 lanes x 4ch =================
// xl2 [N][32] fp16 (dense gather array, 64B rows), xr2 [N][32] fp16.
// row=lane>>3 = edge slot, cl=lane&7, ch=4*cl. Depth-2 prefetch (R1 structure).
__global__ __launch_bounds__(256) void fused_gat2(
    const int* __restrict__ off, const int* __restrict__ csr,
    const __half* __restrict__ xl2, const __half* __restrict__ xr2,
    const float* __restrict__ att,
    const float* __restrict__ scb, const float* __restrict__ shb,
    __half* __restrict__ h2)
{
    int wave = threadIdx.x >> 6;
    int lane = threadIdx.x & 63;
    int node = blockIdx.x * 4 + wave;
    if (node >= NN) return;
    int row = lane >> 3;       // edge slot 0..7
    int cl  = lane & 7;
    int ch  = cl * 4;
    unsigned chb = (unsigned)cl * 8u;        // byte offset of my h4v in a 64B row
    const char* xbase = (const char*)xl2;
    const float LOG2E = 1.44269504088896f;

    h4v xr4 = *(const h4v*)((const char*)xr2 + (size_t)node * 64 + chb);
    h2v xr01 = {xr4[0], xr4[1]}, xr23 = {xr4[2], xr4[3]};
    float4 af = *(const float4*)(att + ch);
    h2v a01 = {(_Float16)(af.x * LOG2E), (_Float16)(af.y * LOG2E)};
    h2v a23 = {(_Float16)(af.z * LOG2E), (_Float16)(af.w * LOG2E)};
    const h2v c2 = {(_Float16)0.2f, (_Float16)0.2f};

    int k0 = off[node], k1 = off[node + 1];
    float acc0 = 0.f, acc1 = 0.f, acc2 = 0.f, acc3 = 0.f, denom = 0.f;

    int rowp8  = row + 8;
    int rowp16 = row + 16;
    int rowp24 = row + 24;

    auto edge = [&](h4v cur, bool valid) {
        h2v xl01 = {cur[0], cur[1]}, xl23 = {cur[2], cur[3]};
        h2v s01 = xl01 + xr01, s23 = xl23 + xr23;
        h2v l01 = hmax2v(s01, s01 * c2);
        h2v l23 = hmax2v(s23, s23 * c2);
        float pp = dot2f(l01, a01, dot2f(l23, a23, 0.f));
        pp = sum8_all(pp);                 // per-edge 32-ch logit (pre-scaled by log2e)
        float wgt = valid ? ex2(pp) : 0.f;
        denom += wgt;
        acc0 = fmaf((float)cur[0], wgt, acc0);
        acc1 = fmaf((float)cur[1], wgt, acc1);
        acc2 = fmaf((float)cur[2], wgt, acc2);
        acc3 = fmaf((float)cur[3], wgt, acc3);
    };

    for (int base = k0; base < k1; base += 64) {
        int nb = min(64, k1 - base);
        int mysrc = (lane < nb) ? csr[base + lane] : 0;
        int nbm1 = nb - 1;
        int i0 = __shfl(mysrc, min(row, nbm1), 64);
        int i1 = __shfl(mysrc, min(rowp8, nbm1), 64);
        h4v c0 = *(const h4v*)(xbase + (((unsigned)i0 << 6) + chb));
        h4v c1 = *(const h4v*)(xbase + (((unsigned)i1 << 6) + chb));
        for (int t = 0; t < nb; t += 16) {
            int i2 = __shfl(mysrc, min(t + rowp16, nbm1), 64);
            int i3 = __shfl(mysrc, min(t + rowp24, nbm1), 64);
            h4v cc2 = *(const h4v*)(xbase + (((unsigned)i2 << 6) + chb));
            h4v cc3 = *(const h4v*)(xbase + (((unsigned)i3 << 6) + chb));
            edge(c0, (t + row) < nb);
            edge(c1, (t + rowp8) < nb);
            c0 = cc2; c1 = cc3;
        }
    }
    // combine the 8 edge slots
    acc0 += __shfl_xor(acc0, 8, 64); acc0 += __shfl_xor(acc0, 16, 64); acc0 += __shfl_xor(acc0, 32, 64);
    acc1 += __shfl_xor(acc1, 8, 64); acc1 += __shfl_xor(acc1, 16, 64); acc1 += __shfl_xor(acc1, 32, 64);
    acc2 += __shfl_xor(acc2, 8, 64); acc2 += __shfl_xor(acc2, 16, 64); acc2 += __shfl_xor(acc2, 32, 64);
    acc3 += __shfl_xor(acc3, 8, 64); acc3 += __shfl_xor(acc3, 16, 64); acc3 += __shfl_xor(acc3, 32, 64);
    denom += __shfl_xor(denom, 8, 64); denom += __shfl_xor(denom, 16, 64); denom += __shfl_xor(denom, 32, 64);
    if (row == 0) {
        float inv = 1.f / (denom + 1e-16f);
        float4 sv = *(const float4*)(scb + ch);
        float4 hv = *(const float4*)(shb + ch);
        float o0 = elu_f(fmaf(acc0 * inv, sv.x, hv.x));
        float o1 = elu_f(fmaf(acc1 * inv, sv.y, hv.y));
        float o2 = elu_f(fmaf(acc2 * inv, sv.z, hv.z));
        float o3 = elu_f(fmaf(acc3 * inv, sv.w, hv.w));
        h4v oh = {(_Float16)o0, (_Float16)o1, (_Float16)o2, (_Float16)o3};
        *(h4v*)(h2 + (size_t)node * 32 + ch) = oh;
    }
}

extern "C" void kernel_launch(void* const* d_in, const int* in_sizes, int n_in,
                              void* d_out, int out_size, void* d_ws, size_t ws_size,
                              hipStream_t stream)
{
    const float* x_pca = (const float*)d_in[0];
    const float* x_bio = (const float*)d_in[1];
    const int*   ei    = (const int*)d_in[2];
    const float* bioW1 = (const float*)d_in[3];
    const float* biob1 = (const float*)d_in[4];
    const float* bn0_g = (const float*)d_in[5];
    const float* bn0_b = (const float*)d_in[6];
    const float* bn0_m = (const float*)d_in[7];
    const float* bn0_v = (const float*)d_in[8];
    const float* bioW2 = (const float*)d_in[9];
    const float* biob2 = (const float*)d_in[10];
    const float* Wl1   = (const float*)d_in[11];
    const float* bl1   = (const float*)d_in[12];
    const float* Wr1   = (const float*)d_in[13];
    const float* br1   = (const float*)d_in[14];
    const float* att1  = (const float*)d_in[15];
    const float* bias1 = (const float*)d_in[16];
    const float* bn1_g = (const float*)d_in[17];
    const float* bn1_b = (const float*)d_in[18];
    const float* bn1_m = (const float*)d_in[19];
    const float* bn1_v = (const float*)d_in[20];
    const float* Wl2   = (const float*)d_in[21];
    const float* bl2   = (const float*)d_in[22];
    const float* Wr2   = (const float*)d_in[23];
    const float* br2   = (const float*)d_in[24];
    const float* att2  = (const float*)d_in[25];
    const float* bias2 = (const float*)d_in[26];
    const float* bn2_g = (const float*)d_in[27];
    const float* bn2_b = (const float*)d_in[28];
    const float* bn2_m = (const float*)d_in[29];
    const float* bn2_v = (const float*)d_in[30];
    const float* predW = (const float*)d_in[31];
    const float* predb = (const float*)d_in[32];

    __half* xh   = (__half*)d_ws;                      // N*96
    __half* xl1  = xh  + (size_t)NN * 96;              // N*128 (dense gather array)
    __half* xr1  = xl1 + (size_t)NN * 128;             // N*128
    __half* h1h  = xr1 + (size_t)NN * 128;             // N*128
    __half* xl2  = h1h + (size_t)NN * 128;             // N*32 (dense gather array)
    __half* xr2  = xl2 + (size_t)NN * 32;              // N*32
    __half* h2h  = xr2 + (size_t)NN * 32;              // N*32
    float*  p4   = (float*)(h2h + (size_t)NN * 32);
    __half* wcat1 = (__half*)p4;                       // 256*96 h
    float*  bcat1 = p4 + 12288;                        // 256
    __half* wcat2 = (__half*)(bcat1 + 256);            // 64*128 h
    float*  bcat2 = bcat1 + 256 + 4096;                // 64
    __half* wpred = (__half*)(bcat2 + 64);             // 64*32 h
    float*  bpred = bcat2 + 64 + 1024;                 // 64
    float*  scb1  = bpred + 64;                        // 128
    float*  shb1  = scb1 + 128;                        // 128
    float*  scb2  = shb1 + 128;                        // 32
    float*  shb2  = scb2 + 32;                         // 32
    int*    ib    = (int*)(shb2 + 32);
    unsigned* ebuf = (unsigned*)ib;                    // NEP
    int*    hist   = ib + NEP;                         // HISTN
    int*    part   = hist + HISTN;                     // 128
    int*    off    = part + 128;                       // NN+1
    int*    csr    = off + NN + 1;                     // NEP

    float* out = (float*)d_out;

    // ---- CSR build (deterministic radix partition) ----
    part_hist<<<NBLK, 256, 0, stream>>>(ei, hist);
    scan_p1<<<HSCAN_BLOCKS, 256, 0, stream>>>(hist, part, HISTN);
    scan_p2<<<1, 128, 0, stream>>>(part, HSCAN_BLOCKS, off);
    scan_p3<<<HSCAN_BLOCKS, 256, 0, stream>>>(hist, part, HISTN);
    part_scatter<<<NBLK, 256, 0, stream>>>(ei, hist, ebuf);
    bucket_csr<<<NBUCK2, 256, 0, stream>>>(hist, ebuf, off, csr);

    // ---- node features (fp16, pca+bio+pad fused) ----
    bio_kernel<<<(NN + 255) / 256, 256, 0, stream>>>(
        x_bio, x_pca, bioW1, biob1, bn0_g, bn0_b, bn0_m, bn0_v, bioW2, biob2, xh);

    // ---- all weight conversions + BN pre-fold ----
    wconvert_all<<<139, 256, 0, stream>>>(
        Wl1, Wr1, bl1, br1, Wl2, Wr2, bl2, br2, predW, predb,
        bias1, bn1_g, bn1_b, bn1_m, bn1_v,
        bias2, bn2_g, bn2_b, bn2_m, bn2_v,
        wcat1, bcat1, wcat2, bcat2, wpred, bpred,
        scb1, shb1, scb2, shb2);

    // ---- layer-1 transform (split: xl cols 0..127, xr cols 128..255) ----
    mfma_gemm<3, 256, 128, false><<<(NN + 63) / 64, 256, 0, stream>>>(
        xh, wcat1, bcat1, xl1, xr1, NN, 0);

    // ---- fused layer-1 edge phase ----
    fused_gat1<<<(NN + 3) / 4, 256, 0, stream>>>(
        off, csr, xl1, xr1, att1, scb1, shb1, h1h);

    // ---- layer-2 transform (split: xl cols 0..31, xr cols 32..63) ----
    mfma_gemm<4, 64, 32, false><<<(NN + 63) / 64, 256, 0, stream>>>(
        h1h, wcat2, bcat2, xl2, xr2, NN, 0);

    // ---- fused layer-2 edge phase ----
    fused_gat2<<<(NN + 3) / 4, 256, 0, stream>>>(
        off, csr, xl2, xr2, att2, scb2, shb2, h2h);

    // ---- prediction head (MFMA, fp32 out) ----
    mfma_gemm<1, 64, 64, true><<<(NN + 63) / 64, 256, 0, stream>>>(
        h2h, wpred, bpred, out, nullptr, NN, 50);
}

// Round 4
// 393.034 us; speedup vs baseline: 1.0514x; 1.0162x over previous
//
#include <hip/hip_runtime.h>
#include <hip/hip_fp16.h>
#include <cstdint>
#include <cstddef>

#define NN 100000
#define NE 1600000
#define NEP (NE + NN)              // 1,700,000
#define NBLK 200                   // partition blocks
#define CHUNK ((NEP + NBLK - 1) / NBLK)   // 8500
#define NBUCK2 ((NN + 255) / 256)  // 391 buckets of 256 dst nodes
#define HISTN (NBUCK2 * NBLK)      // 78,200
#define HSCAN_BLOCKS ((HISTN + 1023) / 1024)  // 77

typedef __attribute__((ext_vector_type(8))) _Float16 half8;
typedef __attribute__((ext_vector_type(4))) _Float16 h4v;
typedef __attribute__((ext_vector_type(2))) _Float16 h2v;
typedef __attribute__((ext_vector_type(4))) float float4v;

__device__ __forceinline__ float elu_f(float x) {
    return x > 0.f ? x : __expf(x) - 1.f;
}

__device__ __forceinline__ float ex2(float x) {
#if __has_builtin(__builtin_amdgcn_exp2f)
    return __builtin_amdgcn_exp2f(x);
#else
    return exp2f(x);
#endif
}

// ---- DPP reduce helpers (pure VALU) ----
template<int CTRL>
__device__ __forceinline__ float dpp_add(float x) {
    int s = __builtin_amdgcn_update_dpp(0, __float_as_int(x), CTRL, 0xF, 0xF, true);
    return x + __int_as_float(s);
}
// allsum within aligned 4-lane quads (one GAT1 head = 4 lanes x 8ch)
__device__ __forceinline__ float sum4_all(float x) {
    x = dpp_add<0xB1>(x); x = dpp_add<0x4E>(x);
    return x;
}
// allsum within aligned 8-lane groups (one GAT2 edge = 8 lanes x 4ch)
__device__ __forceinline__ float sum8_all(float x) {
    x = dpp_add<0xB1>(x); x = dpp_add<0x4E>(x); x = dpp_add<0x141>(x);
    return x;
}

__device__ __forceinline__ float dot2f(h2v a, h2v b, float c) {
#if __has_builtin(__builtin_amdgcn_fdot2)
    return __builtin_amdgcn_fdot2(a, b, c, false);
#else
    return fmaf((float)a[0], (float)b[0], fmaf((float)a[1], (float)b[1], c));
#endif
}

__device__ __forceinline__ h2v hmax2v(h2v a, h2v b) {
#if __has_builtin(__builtin_elementwise_max)
    return __builtin_elementwise_max(a, b);
#else
    __half2 r = __hmax2(*(__half2*)&a, *(__half2*)&b);
    return *(h2v*)&r;
#endif
}

// ================= CSR build: deterministic radix partition =================

__global__ __launch_bounds__(256) void part_hist(const int* __restrict__ ei, int* __restrict__ hist)
{
    __shared__ int cnt[NBUCK2];
    int tid = threadIdx.x, k = blockIdx.x;
    for (int i = tid; i < NBUCK2; i += 256) cnt[i] = 0;
    __syncthreads();
    int e0 = k * CHUNK, e1 = min(e0 + CHUNK, NEP);
    for (int e = e0 + tid; e < e1; e += 256) {
        int dst = (e < NE) ? ei[NE + e] : e - NE;
        atomicAdd(&cnt[dst >> 8], 1);
    }
    __syncthreads();
    for (int i = tid; i < NBUCK2; i += 256) hist[i * NBLK + k] = cnt[i];
}

__global__ __launch_bounds__(256) void scan_p1(const int* __restrict__ src, int* __restrict__ part, int n)
{
    __shared__ int wsum[4];
    int t = threadIdx.x;
    int i0 = blockIdx.x * 1024 + t * 4;
    int s = 0;
    if (i0 + 3 < n) { int4 d = *(const int4*)(src + i0); s = d.x + d.y + d.z + d.w; }
    else { for (int k = 0; k < 4; k++) if (i0 + k < n) s += src[i0 + k]; }
    for (int d = 1; d < 64; d <<= 1) s += __shfl_xor(s, d, 64);
    if ((t & 63) == 0) wsum[t >> 6] = s;
    __syncthreads();
    if (t == 0) part[blockIdx.x] = wsum[0] + wsum[1] + wsum[2] + wsum[3];
}

__global__ __launch_bounds__(128) void scan_p2(int* __restrict__ part, int nb, int* __restrict__ off)
{
    __shared__ int wt[2];
    int t = threadIdx.x;
    int lane = t & 63, w = t >> 6;
    int v = (t < nb) ? part[t] : 0;
    int x = v;
    for (int d = 1; d < 64; d <<= 1) { int y = __shfl_up(x, d, 64); if (lane >= d) x += y; }
    if (lane == 63) wt[w] = x;
    __syncthreads();
    int base = (w == 1) ? wt[0] : 0;
    int excl = base + x - v;
    if (t < nb) part[t] = excl;
    if (t == 0) off[NN] = NEP;
}

__global__ __launch_bounds__(256) void scan_p3(int* __restrict__ data, const int* __restrict__ part, int n)
{
    __shared__ int wsum[4];
    int t = threadIdx.x, lane = t & 63, w = t >> 6;
    int i0 = blockIdx.x * 1024 + t * 4;
    int d0 = 0, d1 = 0, d2 = 0, d3 = 0;
    if (i0 + 3 < n) { int4 d = *(const int4*)(data + i0); d0 = d.x; d1 = d.y; d2 = d.z; d3 = d.w; }
    else if (i0 < n) {
        d0 = data[i0];
        if (i0 + 1 < n) d1 = data[i0 + 1];
        if (i0 + 2 < n) d2 = data[i0 + 2];
    }
    int s = d0 + d1 + d2 + d3;
    int x = s;
    for (int d = 1; d < 64; d <<= 1) { int y = __shfl_up(x, d, 64); if (lane >= d) x += y; }
    if (lane == 63) wsum[w] = x;
    __syncthreads();
    int wb = 0;
    for (int i = 0; i < w; i++) wb += wsum[i];
    int base = part[blockIdx.x] + wb + x - s;
    if (i0 < n)     data[i0]     = base;
    if (i0 + 1 < n) data[i0 + 1] = base + d0;
    if (i0 + 2 < n) data[i0 + 2] = base + d0 + d1;
    if (i0 + 3 < n) data[i0 + 3] = base + d0 + d1 + d2;
}

__global__ __launch_bounds__(256) void part_scatter(const int* __restrict__ ei,
                                                    const int* __restrict__ hist,
                                                    unsigned* __restrict__ ebuf)
{
    __shared__ int cur[NBUCK2];
    int tid = threadIdx.x, k = blockIdx.x;
    for (int i = tid; i < NBUCK2; i += 256) cur[i] = hist[i * NBLK + k];
    __syncthreads();
    int e0 = k * CHUNK, e1 = min(e0 + CHUNK, NEP);
    for (int e = e0 + tid; e < e1; e += 256) {
        int src, dst;
        if (e < NE) { src = ei[e]; dst = ei[NE + e]; } else { src = dst = e - NE; }
        int pos = atomicAdd(&cur[dst >> 8], 1);
        ebuf[pos] = (unsigned)src | ((unsigned)(dst & 255) << 24);
    }
}

__global__ __launch_bounds__(256) void bucket_csr(const int* __restrict__ hist,
                                                  const unsigned* __restrict__ ebuf,
                                                  int* __restrict__ off, int* __restrict__ csr)
{
    __shared__ int cnt[256];
    __shared__ int cur[256];
    __shared__ int wsum[4];
    int b = blockIdx.x;
    int d0 = b << 8;
    int tid = threadIdx.x;
    int e0 = hist[b * NBLK];
    int e1 = (b + 1 < NBUCK2) ? hist[(b + 1) * NBLK] : NEP;
    cnt[tid] = 0;
    __syncthreads();
    for (int i = e0 + tid; i < e1; i += 256) atomicAdd(&cnt[ebuf[i] >> 24], 1);
    __syncthreads();
    int c = cnt[tid];
    int x = c;
    int lane = tid & 63, w = tid >> 6;
    for (int d = 1; d < 64; d <<= 1) { int y = __shfl_up(x, d, 64); if (lane >= d) x += y; }
    if (lane == 63) wsum[w] = x;
    __syncthreads();
    int wb = 0;
    for (int i = 0; i < w; i++) wb += wsum[i];
    int excl = wb + x - c;
    cur[tid] = e0 + excl;
    int node = d0 + tid;
    if (node < NN) off[node] = e0 + excl;
    __syncthreads();
    for (int i = e0 + tid; i < e1; i += 256) {
        unsigned v = ebuf[i];
        int p = atomicAdd(&cur[v >> 24], 1);
        csr[p] = (int)(v & 0xFFFFFF);
    }
}

// ================= node feature prep (fp16 x [N][96]; bio + pca + pad fused) =================

__global__ __launch_bounds__(256) void bio_kernel(
    const float* __restrict__ xb, const float* __restrict__ xp,
    const float* __restrict__ W1, const float* __restrict__ b1,
    const float* __restrict__ g0, const float* __restrict__ bb0,
    const float* __restrict__ m0, const float* __restrict__ v0,
    const float* __restrict__ W2, const float* __restrict__ b2,
    __half* __restrict__ xh)
{
    __shared__ float sW1[16*64], sW2[16*16], sb1[16], sb2[16], ss[16], st[16];
    int tid = threadIdx.x;
    for (int idx = tid; idx < 1024; idx += 256) sW1[idx] = W1[idx];
    if (tid < 256) sW2[tid] = W2[tid];
    if (tid < 16) {
        sb1[tid] = b1[tid]; sb2[tid] = b2[tid];
        float s = g0[tid] * rsqrtf(v0[tid] + 1e-5f);
        ss[tid] = s; st[tid] = bb0[tid] - m0[tid] * s;
    }
    __syncthreads();
    int i = blockIdx.x * 256 + tid;
    if (i >= NN) return;
    float bio[64];
    const float4* p = (const float4*)(xb + (size_t)i * 64);
    #pragma unroll
    for (int q = 0; q < 16; q++) {
        float4 f = p[q];
        bio[q*4] = f.x; bio[q*4+1] = f.y; bio[q*4+2] = f.z; bio[q*4+3] = f.w;
    }
    float t1[16];
    #pragma unroll
    for (int j = 0; j < 16; j++) {
        float acc = sb1[j];
        #pragma unroll
        for (int k = 0; k < 64; k++) acc += bio[k] * sW1[j*64 + k];
        acc = acc * ss[j] + st[j];
        t1[j] = elu_f(acc);
    }
    __half* xrow = xh + (size_t)i * 96;
    const float* xpr = xp + (size_t)i * 50;
    #pragma unroll
    for (int j = 0; j < 25; j++) {
        float2 f = *(const float2*)(xpr + 2 * j);
        *(__half2*)(xrow + 2 * j) = __floats2half2_rn(f.x, f.y);
    }
    #pragma unroll
    for (int j = 0; j < 16; j++) {
        float acc = sb2[j];
        #pragma unroll
        for (int k = 0; k < 16; k++) acc += t1[k] * sW2[j*16 + k];
        xrow[50 + j] = __float2half(elu_f(acc));
    }
    __half2 z2 = __floats2half2_rn(0.f, 0.f);
    #pragma unroll
    for (int j = 0; j < 15; j++) *(__half2*)(xrow + 66 + 2 * j) = z2;
}

// ================= all weight conversions + BN/bias pre-fold in one launch =================

__global__ __launch_bounds__(256) void wconvert_all(
    const float* __restrict__ Wl1, const float* __restrict__ Wr1,
    const float* __restrict__ bl1, const float* __restrict__ br1,
    const float* __restrict__ Wl2, const float* __restrict__ Wr2,
    const float* __restrict__ bl2, const float* __restrict__ br2,
    const float* __restrict__ predW, const float* __restrict__ predb,
    const float* __restrict__ bias1, const float* __restrict__ bn1g,
    const float* __restrict__ bn1b, const float* __restrict__ bn1m,
    const float* __restrict__ bn1v,
    const float* __restrict__ bias2, const float* __restrict__ bn2g,
    const float* __restrict__ bn2b, const float* __restrict__ bn2m,
    const float* __restrict__ bn2v,
    __half* __restrict__ wcat1, float* __restrict__ bcat1,
    __half* __restrict__ wcat2, float* __restrict__ bcat2,
    __half* __restrict__ wpred, float* __restrict__ bpred,
    float* __restrict__ scb1, float* __restrict__ shb1,
    float* __restrict__ scb2, float* __restrict__ shb2)
{
    int t = blockIdx.x * 256 + threadIdx.x;
    if (t < 256 * 96) {
        int j = t / 96, k = t - j * 96;
        float v = (k < 66) ? ((j < 128) ? Wl1[j * 66 + k] : Wr1[(j - 128) * 66 + k]) : 0.f;
        wcat1[t] = __float2half(v);
    }
    int u = t - 256 * 96;
    if (u >= 0 && u < 64 * 128) {
        int j = u >> 7, k = u & 127;
        float v = (j < 32) ? Wl2[j * 128 + k] : Wr2[(j - 32) * 128 + k];
        wcat2[u] = __float2half(v);
    }
    int w = u - 64 * 128;
    if (w >= 0 && w < 64 * 32) {
        int j = w >> 5;
        wpred[w] = __float2half(j < 50 ? predW[w] : 0.f);
    }
    int z = w - 64 * 32;
    if (z >= 0 && z < 256) bcat1[z] = (z < 128) ? bl1[z] : br1[z - 128];
    int z2 = z - 256;
    if (z2 >= 0 && z2 < 64) bcat2[z2] = (z2 < 32) ? bl2[z2] : br2[z2 - 32];
    int z3 = z2 - 64;
    if (z3 >= 0 && z3 < 64) bpred[z3] = (z3 < 50) ? predb[z3] : 0.f;
    int z4 = z3 - 64;
    if (z4 >= 0 && z4 < 128) {
        float sc = bn1g[z4] * rsqrtf(bn1v[z4] + 1e-5f);
        scb1[z4] = sc;
        shb1[z4] = bn1b[z4] + (bias1[z4] - bn1m[z4]) * sc;
    }
    int z5 = z4 - 128;
    if (z5 >= 0 && z5 < 32) {
        float sc = bn2g[z5] * rsqrtf(bn2v[z5] + 1e-5f);
        scb2[z5] = sc;
        shb2[z5] = bn2b[z5] + (bias2[z5] - bn2m[z5]) * sc;
    }
}

// ================= MFMA f16 GEMM (column-blocked; split output at NSPL) =================
// Block computes cols [blockIdx.y*NCB, +NCB). Cols < NSPL -> out1 (stride NSPL),
// else -> out2 (stride NC-NSPL). NCB=128 for GEMM1 halves LDS -> 4 blocks/CU.
template<int KT, int NC, int NCB, int NSPL, bool FOUT>
__global__ __launch_bounds__(256) void mfma_gemm(
    const __half* __restrict__ in, const __half* __restrict__ wcat,
    const float* __restrict__ bcat, void* __restrict__ outv, void* __restrict__ outv2,
    int n, int ncol)
{
    constexpr int K = KT * 32;
    constexpr int KP = K + 8;
    __shared__ __half sW[NCB * KP];
    __shared__ __half sX[64 * KP];
    __shared__ float sB[NCB];
    int tid = threadIdx.x;
    int co = blockIdx.y * NCB;
    for (int idx = tid * 8; idx < NCB * K; idx += 256 * 8) {
        int r = idx / K, c = idx - r * K;
        *(half8*)(&sW[r * KP + c]) = *(const half8*)(&wcat[(size_t)(co + r) * K + c]);
    }
    for (int idx = tid; idx < NCB; idx += 256) sB[idx] = bcat[co + idx];
    int row0 = blockIdx.x * 64;
    half8 hz = {0, 0, 0, 0, 0, 0, 0, 0};
    for (int idx = tid * 8; idx < 64 * K; idx += 256 * 8) {
        int r = idx / K, c = idx - r * K;
        int gr = row0 + r;
        half8 v = (gr < n) ? *(const half8*)(&in[(size_t)gr * K + c]) : hz;
        *(half8*)(&sX[r * KP + c]) = v;
    }
    __syncthreads();
    int w = tid >> 6, lane = tid & 63;
    int m = lane & 15, quad = lane >> 4;
    half8 a[KT];
    #pragma unroll
    for (int kt = 0; kt < KT; kt++)
        a[kt] = *(const half8*)(&sX[(w * 16 + m) * KP + kt * 32 + quad * 8]);
    #pragma unroll 1
    for (int nt = 0; nt < NCB / 16; nt++) {
        float4v acc = {0.f, 0.f, 0.f, 0.f};
        #pragma unroll
        for (int kt = 0; kt < KT; kt++) {
            half8 bfrag = *(const half8*)(&sW[(nt * 16 + m) * KP + kt * 32 + quad * 8]);
            acc = __builtin_amdgcn_mfma_f32_16x16x32_f16(a[kt], bfrag, acc, 0, 0, 0);
        }
        int col = co + nt * 16 + m;
        float bias = sB[nt * 16 + m];
        #pragma unroll
        for (int i = 0; i < 4; i++) {
            int r = row0 + w * 16 + quad * 4 + i;
            if (r < n) {
                if (FOUT) { if (col < ncol) ((float*)outv)[(size_t)r * ncol + col] = acc[i] + bias; }
                else if (col < NSPL)
                    ((__half*)outv)[(size_t)r * NSPL + col] = __float2half(acc[i] + bias);
                else
                    ((__half*)outv2)[(size_t)r * (NC - NSPL) + (col - NSPL)] = __float2half(acc[i] + bias);
            }
        }
    }
}

// ================= fused GATv2 layer 1: 4 edges/iter x 16 lanes x 8ch =================
// xl [N][128] fp16 (dense gather array), xr [N][128] fp16 (streamed once/node).
// row=lane>>4 = edge slot, cl=lane&15, ch=8*cl. Head = 32 ch = 4 lanes -> sum4_all.
// Depth-2 prefetch. No index clamps: lanes>=nb hold mysrc=0 (row 0 gather is
// safe), shfl index wraps mod 64, and the `valid` mask zeroes the weight.
// att pre-scaled by log2(e): wgt = exp2(pp). BN+bias pre-folded.
__global__ __launch_bounds__(256) void fused_gat1(
    const int* __restrict__ off, const int* __restrict__ csr,
    const __half* __restrict__ xl, const __half* __restrict__ xr,
    const float* __restrict__ att,
    const float* __restrict__ scb, const float* __restrict__ shb,
    __half* __restrict__ h1)
{
    int wave = threadIdx.x >> 6;
    int lane = threadIdx.x & 63;
    int node = blockIdx.x * 4 + wave;
    if (node >= NN) return;
    int row = lane >> 4;       // edge slot 0..3
    int cl  = lane & 15;
    int ch  = cl * 8;
    unsigned chb = (unsigned)cl * 16u;       // byte offset of my half8 in a 256B row
    const char* xbase = (const char*)xl;
    const float LOG2E = 1.44269504088896f;

    half8 xr8 = *(const half8*)((const char*)xr + (size_t)node * 256 + chb);
    float4 af0 = *(const float4*)(att + ch);
    float4 af1 = *(const float4*)(att + ch + 4);
    h2v a01 = {(_Float16)(af0.x * LOG2E), (_Float16)(af0.y * LOG2E)};
    h2v a23 = {(_Float16)(af0.z * LOG2E), (_Float16)(af0.w * LOG2E)};
    h2v a45 = {(_Float16)(af1.x * LOG2E), (_Float16)(af1.y * LOG2E)};
    h2v a67 = {(_Float16)(af1.z * LOG2E), (_Float16)(af1.w * LOG2E)};
    h2v xr01 = {xr8[0], xr8[1]}, xr23 = {xr8[2], xr8[3]};
    h2v xr45 = {xr8[4], xr8[5]}, xr67 = {xr8[6], xr8[7]};
    const h2v c2 = {(_Float16)0.2f, (_Float16)0.2f};

    int k0 = off[node], k1 = off[node + 1];
    float acc0 = 0.f, acc1 = 0.f, acc2 = 0.f, acc3 = 0.f;
    float acc4 = 0.f, acc5 = 0.f, acc6 = 0.f, acc7 = 0.f, denom = 0.f;

    int rowp4  = row + 4;
    int rowp8  = row + 8;
    int rowp12 = row + 12;

    auto edge = [&](half8 cur, bool valid) {
        h2v xl01 = {cur[0], cur[1]}, xl23 = {cur[2], cur[3]};
        h2v xl45 = {cur[4], cur[5]}, xl67 = {cur[6], cur[7]};
        h2v s01 = xl01 + xr01, s23 = xl23 + xr23;
        h2v s45 = xl45 + xr45, s67 = xl67 + xr67;
        h2v l01 = hmax2v(s01, s01 * c2);
        h2v l23 = hmax2v(s23, s23 * c2);
        h2v l45 = hmax2v(s45, s45 * c2);
        h2v l67 = hmax2v(s67, s67 * c2);
        float pp = dot2f(l01, a01, dot2f(l23, a23, dot2f(l45, a45, dot2f(l67, a67, 0.f))));
        pp = sum4_all(pp);                 // per-head (quad) logit (pre-scaled by log2e)
        float wgt = valid ? ex2(pp) : 0.f;
        denom += wgt;
        acc0 = fmaf((float)cur[0], wgt, acc0);
        acc1 = fmaf((float)cur[1], wgt, acc1);
        acc2 = fmaf((float)cur[2], wgt, acc2);
        acc3 = fmaf((float)cur[3], wgt, acc3);
        acc4 = fmaf((float)cur[4], wgt, acc4);
        acc5 = fmaf((float)cur[5], wgt, acc5);
        acc6 = fmaf((float)cur[6], wgt, acc6);
        acc7 = fmaf((float)cur[7], wgt, acc7);
    };

    for (int base = k0; base < k1; base += 64) {
        int nb = min(64, k1 - base);
        int mysrc = (lane < nb) ? csr[base + lane] : 0;
        int i0 = __shfl(mysrc, row, 64);
        int i1 = __shfl(mysrc, rowp4, 64);
        half8 c0 = *(const half8*)(xbase + (((unsigned)i0 << 8) + chb));
        half8 c1 = *(const half8*)(xbase + (((unsigned)i1 << 8) + chb));
        #pragma unroll 2
        for (int t = 0; t < nb; t += 8) {
            int i2 = __shfl(mysrc, t + rowp8, 64);
            int i3 = __shfl(mysrc, t + rowp12, 64);
            half8 cc2 = *(const half8*)(xbase + (((unsigned)i2 << 8) + chb));
            half8 cc3 = *(const half8*)(xbase + (((unsigned)i3 << 8) + chb));
            edge(c0, (t + row) < nb);
            edge(c1, (t + rowp4) < nb);
            c0 = cc2; c1 = cc3;
        }
    }
    // combine the 4 edge slots
    acc0 += __shfl_xor(acc0, 16, 64); acc0 += __shfl_xor(acc0, 32, 64);
    acc1 += __shfl_xor(acc1, 16, 64); acc1 += __shfl_xor(acc1, 32, 64);
    acc2 += __shfl_xor(acc2, 16, 64); acc2 += __shfl_xor(acc2, 32, 64);
    acc3 += __shfl_xor(acc3, 16, 64); acc3 += __shfl_xor(acc3, 32, 64);
    acc4 += __shfl_xor(acc4, 16, 64); acc4 += __shfl_xor(acc4, 32, 64);
    acc5 += __shfl_xor(acc5, 16, 64); acc5 += __shfl_xor(acc5, 32, 64);
    acc6 += __shfl_xor(acc6, 16, 64); acc6 += __shfl_xor(acc6, 32, 64);
    acc7 += __shfl_xor(acc7, 16, 64); acc7 += __shfl_xor(acc7, 32, 64);
    denom += __shfl_xor(denom, 16, 64); denom += __shfl_xor(denom, 32, 64);
    if (row == 0) {
        float inv = 1.f / (denom + 1e-16f);
        float4 s0 = *(const float4*)(scb + ch), s1 = *(const float4*)(scb + ch + 4);
        float4 h0 = *(const float4*)(shb + ch), h1f = *(const float4*)(shb + ch + 4);
        float o[8];
        o[0] = elu_f(fmaf(acc0 * inv, s0.x, h0.x));
        o[1] = elu_f(fmaf(acc1 * inv, s0.y, h0.y));
        o[2] = elu_f(fmaf(acc2 * inv, s0.z, h0.z));
        o[3] = elu_f(fmaf(acc3 * inv, s0.w, h0.w));
        o[4] = elu_f(fmaf(acc4 * inv, s1.x, h1f.x));
        o[5] = elu_f(fmaf(acc5 * inv, s1.y, h1f.y));
        o[6] = elu_f(fmaf(acc6 * inv, s1.z, h1f.z));
        o[7] = elu_f(fmaf(acc7 * inv, s1.w, h1f.w));
        half8 oh = {(_Float16)o[0], (_Float16)o[1], (_Float16)o[2], (_Float16)o[3],
                    (_Float16)o[4], (_Float16)o[5], (_Float16)o[6], (_Float16)o[7]};
        *(half8*)(h1 + (size_t)node * 128 + ch) = oh;
    }
}

// ================= fused GATv2 layer 2: 8 edges/iter x 8 lanes x 4ch =================
// xl2 [N][32] fp16 (dense gather array, 64B rows), xr2 [N][32] fp16.
// row=lane>>3 = edge slot, cl=lane&7, ch=4*cl. Depth-2 prefetch, no clamps.
__global__ __launch_bounds__(256) void fused_gat2(
    const int* __restrict__ off, const int* __restrict__ csr,
    const __half* __restrict__ xl2, const __half* __restrict__ xr2,
    const float* __restrict__ att,
    const float* __restrict__ scb, const float* __restrict__ shb,
    __half* __restrict__ h2)
{
    int wave = threadIdx.x >> 6;
    int lane = threadIdx.x & 63;
    int node = blockIdx.x * 4 + wave;
    if (node >= NN) return;
    int row = lane >> 3;       // edge slot 0..7
    int cl  = lane & 7;
    int ch  = cl * 4;
    unsigned chb = (unsigned)cl * 8u;        // byte offset of my h4v in a 64B row
    const char* xbase = (const char*)xl2;
    const float LOG2E = 1.44269504088896f;

    h4v xr4 = *(const h4v*)((const char*)xr2 + (size_t)node * 64 + chb);
    h2v xr01 = {xr4[0], xr4[1]}, xr23 = {xr4[2], xr4[3]};
    float4 af = *(const float4*)(att + ch);
    h2v a01 = {(_Float16)(af.x * LOG2E), (_Float16)(af.y * LOG2E)};
    h2v a23 = {(_Float16)(af.z * LOG2E), (_Float16)(af.w * LOG2E)};
    const h2v c2 = {(_Float16)0.2f, (_Float16)0.2f};

    int k0 = off[node], k1 = off[node + 1];
    float acc0 = 0.f, acc1 = 0.f, acc2 = 0.f, acc3 = 0.f, denom = 0.f;

    int rowp8  = row + 8;
    int rowp16 = row + 16;
    int rowp24 = row + 24;

    auto edge = [&](h4v cur, bool valid) {
        h2v xl01 = {cur[0], cur[1]}, xl23 = {cur[2], cur[3]};
        h2v s01 = xl01 + xr01, s23 = xl23 + xr23;
        h2v l01 = hmax2v(s01, s01 * c2);
        h2v l23 = hmax2v(s23, s23 * c2);
        float pp = dot2f(l01, a01, dot2f(l23, a23, 0.f));
        pp = sum8_all(pp);                 // per-edge 32-ch logit (pre-scaled by log2e)
        float wgt = valid ? ex2(pp) : 0.f;
        denom += wgt;
        acc0 = fmaf((float)cur[0], wgt, acc0);
        acc1 = fmaf((float)cur[1], wgt, acc1);
        acc2 = fmaf((float)cur[2], wgt, acc2);
        acc3 = fmaf((float)cur[3], wgt, acc3);
    };

    for (int base = k0; base < k1; base += 64) {
        int nb = min(64, k1 - base);
        int mysrc = (lane < nb) ? csr[base + lane] : 0;
        int i0 = __shfl(mysrc, row, 64);
        int i1 = __shfl(mysrc, rowp8, 64);
        h4v c0 = *(const h4v*)(xbase + (((unsigned)i0 << 6) + chb));
        h4v c1 = *(const h4v*)(xbase + (((unsigned)i1 << 6) + chb));
        #pragma unroll 2
        for (int t = 0; t < nb; t += 16) {
            int i2 = __shfl(mysrc, t + rowp16, 64);
            int i3 = __shfl(mysrc, t + rowp24, 64);
            h4v cc2 = *(const h4v*)(xbase + (((unsigned)i2 << 6) + chb));
            h4v cc3 = *(const h4v*)(xbase + (((unsigned)i3 << 6) + chb));
            edge(c0, (t + row) < nb);
            edge(c1, (t + rowp8) < nb);
            c0 = cc2; c1 = cc3;
        }
    }
    // combine the 8 edge slots
    acc0 += __shfl_xor(acc0, 8, 64); acc0 += __shfl_xor(acc0, 16, 64); acc0 += __shfl_xor(acc0, 32, 64);
    acc1 += __shfl_xor(acc1, 8, 64); acc1 += __shfl_xor(acc1, 16, 64); acc1 += __shfl_xor(acc1, 32, 64);
    acc2 += __shfl_xor(acc2, 8, 64); acc2 += __shfl_xor(acc2, 16, 64); acc2 += __shfl_xor(acc2, 32, 64);
    acc3 += __shfl_xor(acc3, 8, 64); acc3 += __shfl_xor(acc3, 16, 64); acc3 += __shfl_xor(acc3, 32, 64);
    denom += __shfl_xor(denom, 8, 64); denom += __shfl_xor(denom, 16, 64); denom += __shfl_xor(denom, 32, 64);
    if (row == 0) {
        float inv = 1.f / (denom + 1e-16f);
        float4 sv = *(const float4*)(scb + ch);
        float4 hv = *(const float4*)(shb + ch);
        float o0 = elu_f(fmaf(acc0 * inv, sv.x, hv.x));
        float o1 = elu_f(fmaf(acc1 * inv, sv.y, hv.y));
        float o2 = elu_f(fmaf(acc2 * inv, sv.z, hv.z));
        float o3 = elu_f(fmaf(acc3 * inv, sv.w, hv.w));
        h4v oh = {(_Float16)o0, (_Float16)o1, (_Float16)o2, (_Float16)o3};
        *(h4v*)(h2 + (size_t)node * 32 + ch) = oh;
    }
}

extern "C" void kernel_launch(void* const* d_in, const int* in_sizes, int n_in,
                              void* d_out, int out_size, void* d_ws, size_t ws_size,
                              hipStream_t stream)
{
    const float* x_pca = (const float*)d_in[0];
    const float* x_bio = (const float*)d_in[1];
    const int*   ei    = (const int*)d_in[2];
    const float* bioW1 = (const float*)d_in[3];
    const float* biob1 = (const float*)d_in[4];
    const float* bn0_g = (const float*)d_in[5];
    const float* bn0_b = (const float*)d_in[6];
    const float* bn0_m = (const float*)d_in[7];
    const float* bn0_v = (const float*)d_in[8];
    const float* bioW2 = (const float*)d_in[9];
    const float* biob2 = (const float*)d_in[10];
    const float* Wl1   = (const float*)d_in[11];
    const float* bl1   = (const float*)d_in[12];
    const float* Wr1   = (const float*)d_in[13];
    const float* br1   = (const float*)d_in[14];
    const float* att1  = (const float*)d_in[15];
    const float* bias1 = (const float*)d_in[16];
    const float* bn1_g = (const float*)d_in[17];
    const float* bn1_b = (const float*)d_in[18];
    const float* bn1_m = (const float*)d_in[19];
    const float* bn1_v = (const float*)d_in[20];
    const float* Wl2   = (const float*)d_in[21];
    const float* bl2   = (const float*)d_in[22];
    const float* Wr2   = (const float*)d_in[23];
    const float* br2   = (const float*)d_in[24];
    const float* att2  = (const float*)d_in[25];
    const float* bias2 = (const float*)d_in[26];
    const float* bn2_g = (const float*)d_in[27];
    const float* bn2_b = (const float*)d_in[28];
    const float* bn2_m = (const float*)d_in[29];
    const float* bn2_v = (const float*)d_in[30];
    const float* predW = (const float*)d_in[31];
    const float* predb = (const float*)d_in[32];

    __half* xh   = (__half*)d_ws;                      // N*96
    __half* xl1  = xh  + (size_t)NN * 96;              // N*128 (dense gather array)
    __half* xr1  = xl1 + (size_t)NN * 128;             // N*128
    __half* h1h  = xr1 + (size_t)NN * 128;             // N*128
    __half* xl2  = h1h + (size_t)NN * 128;             // N*32 (dense gather array)
    __half* xr2  = xl2 + (size_t)NN * 32;              // N*32
    __half* h2h  = xr2 + (size_t)NN * 32;              // N*32
    float*  p4   = (float*)(h2h + (size_t)NN * 32);
    __half* wcat1 = (__half*)p4;                       // 256*96 h
    float*  bcat1 = p4 + 12288;                        // 256
    __half* wcat2 = (__half*)(bcat1 + 256);            // 64*128 h
    float*  bcat2 = bcat1 + 256 + 4096;                // 64
    __half* wpred = (__half*)(bcat2 + 64);             // 64*32 h
    float*  bpred = bcat2 + 64 + 1024;                 // 64
    float*  scb1  = bpred + 64;                        // 128
    float*  shb1  = scb1 + 128;                        // 128
    float*  scb2  = shb1 + 128;                        // 32
    float*  shb2  = scb2 + 32;                         // 32
    int*    ib    = (int*)(shb2 + 32);
    unsigned* ebuf = (unsigned*)ib;                    // NEP
    int*    hist   = ib + NEP;                         // HISTN
    int*    part   = hist + HISTN;                     // 128
    int*    off    = part + 128;                       // NN+1
    int*    csr    = off + NN + 1;                     // NEP

    float* out = (float*)d_out;

    // ---- CSR build (deterministic radix partition) ----
    part_hist<<<NBLK, 256, 0, stream>>>(ei, hist);
    scan_p1<<<HSCAN_BLOCKS, 256, 0, stream>>>(hist, part, HISTN);
    scan_p2<<<1, 128, 0, stream>>>(part, HSCAN_BLOCKS, off);
    scan_p3<<<HSCAN_BLOCKS, 256, 0, stream>>>(hist, part, HISTN);
    part_scatter<<<NBLK, 256, 0, stream>>>(ei, hist, ebuf);
    bucket_csr<<<NBUCK2, 256, 0, stream>>>(hist, ebuf, off, csr);

    // ---- node features (fp16, pca+bio+pad fused) ----
    bio_kernel<<<(NN + 255) / 256, 256, 0, stream>>>(
        x_bio, x_pca, bioW1, biob1, bn0_g, bn0_b, bn0_m, bn0_v, bioW2, biob2, xh);

    // ---- all weight conversions + BN pre-fold ----
    wconvert_all<<<139, 256, 0, stream>>>(
        Wl1, Wr1, bl1, br1, Wl2, Wr2, bl2, br2, predW, predb,
        bias1, bn1_g, bn1_b, bn1_m, bn1_v,
        bias2, bn2_g, bn2_b, bn2_m, bn2_v,
        wcat1, bcat1, wcat2, bcat2, wpred, bpred,
        scb1, shb1, scb2, shb2);

    // ---- layer-1 transform (2 column blocks: y=0 -> xl1, y=1 -> xr1) ----
    mfma_gemm<3, 256, 128, 128, false><<<dim3((NN + 63) / 64, 2), 256, 0, stream>>>(
        xh, wcat1, bcat1, xl1, xr1, NN, 0);

    // ---- fused layer-1 edge phase ----
    fused_gat1<<<(NN + 3) / 4, 256, 0, stream>>>(
        off, csr, xl1, xr1, att1, scb1, shb1, h1h);

    // ---- layer-2 transform (split: xl cols 0..31, xr cols 32..63) ----
    mfma_gemm<4, 64, 64, 32, false><<<dim3((NN + 63) / 64, 1), 256, 0, stream>>>(
        h1h, wcat2, bcat2, xl2, xr2, NN, 0);

    // ---- fused layer-2 edge phase ----
    fused_gat2<<<(NN + 3) / 4, 256, 0, stream>>>(
        off, csr, xl2, xr2, att2, scb2, shb2, h2h);

    // ---- prediction head (MFMA, fp32 out) ----
    mfma_gemm<1, 64, 64, 64, true><<<dim3((NN + 63) / 64, 1), 256, 0, stream>>>(
        h2h, wpred, bpred, out, nullptr, NN, 50);
}

// Round 5
// 390.341 us; speedup vs baseline: 1.0587x; 1.0069x over previous
//
#include <hip/hip_runtime.h>
#include <hip/hip_fp16.h>
#include <cstdint>
#include <cstddef>

#define NN 100000
#define NE 1600000
#define NEP (NE + NN)              // 1,700,000
#define NBLK 200                   // partition blocks
#define CHUNK ((NEP + NBLK - 1) / NBLK)   // 8500
#define NBUCK2 ((NN + 255) / 256)  // 391 buckets of 256 dst nodes
#define HISTN (NBUCK2 * NBLK)      // 78,200
#define HSCAN_BLOCKS ((HISTN + 1023) / 1024)  // 77

typedef __attribute__((ext_vector_type(8))) _Float16 half8;
typedef __attribute__((ext_vector_type(4))) _Float16 h4v;
typedef __attribute__((ext_vector_type(2))) _Float16 h2v;
typedef __attribute__((ext_vector_type(4))) float float4v;

__device__ __forceinline__ float elu_f(float x) {
    return x > 0.f ? x : __expf(x) - 1.f;
}

__device__ __forceinline__ float ex2(float x) {
#if __has_builtin(__builtin_amdgcn_exp2f)
    return __builtin_amdgcn_exp2f(x);
#else
    return exp2f(x);
#endif
}

// ---- DPP reduce helpers (pure VALU) ----
template<int CTRL>
__device__ __forceinline__ float dpp_add(float x) {
    int s = __builtin_amdgcn_update_dpp(0, __float_as_int(x), CTRL, 0xF, 0xF, true);
    return x + __int_as_float(s);
}
// allsum within aligned 4-lane quads (one GAT1 head = 4 lanes x 8ch)
__device__ __forceinline__ float sum4_all(float x) {
    x = dpp_add<0xB1>(x); x = dpp_add<0x4E>(x);
    return x;
}
// allsum within aligned 8-lane groups (one GAT2 edge = 8 lanes x 4ch)
__device__ __forceinline__ float sum8_all(float x) {
    x = dpp_add<0xB1>(x); x = dpp_add<0x4E>(x); x = dpp_add<0x141>(x);
    return x;
}

__device__ __forceinline__ float dot2f(h2v a, h2v b, float c) {
#if __has_builtin(__builtin_amdgcn_fdot2)
    return __builtin_amdgcn_fdot2(a, b, c, false);
#else
    return fmaf((float)a[0], (float)b[0], fmaf((float)a[1], (float)b[1], c));
#endif
}

__device__ __forceinline__ h2v hmax2v(h2v a, h2v b) {
#if __has_builtin(__builtin_elementwise_max)
    return __builtin_elementwise_max(a, b);
#else
    __half2 r = __hmax2(*(__half2*)&a, *(__half2*)&b);
    return *(h2v*)&r;
#endif
}

// ================= CSR build: deterministic radix partition =================

__global__ __launch_bounds__(256) void part_hist(const int* __restrict__ ei, int* __restrict__ hist)
{
    __shared__ int cnt[NBUCK2];
    int tid = threadIdx.x, k = blockIdx.x;
    for (int i = tid; i < NBUCK2; i += 256) cnt[i] = 0;
    __syncthreads();
    int e0 = k * CHUNK, e1 = min(e0 + CHUNK, NEP);
    for (int e = e0 + tid; e < e1; e += 256) {
        int dst = (e < NE) ? ei[NE + e] : e - NE;
        atomicAdd(&cnt[dst >> 8], 1);
    }
    __syncthreads();
    for (int i = tid; i < NBUCK2; i += 256) hist[i * NBLK + k] = cnt[i];
}

__global__ __launch_bounds__(256) void scan_p1(const int* __restrict__ src, int* __restrict__ part, int n)
{
    __shared__ int wsum[4];
    int t = threadIdx.x;
    int i0 = blockIdx.x * 1024 + t * 4;
    int s = 0;
    if (i0 + 3 < n) { int4 d = *(const int4*)(src + i0); s = d.x + d.y + d.z + d.w; }
    else { for (int k = 0; k < 4; k++) if (i0 + k < n) s += src[i0 + k]; }
    for (int d = 1; d < 64; d <<= 1) s += __shfl_xor(s, d, 64);
    if ((t & 63) == 0) wsum[t >> 6] = s;
    __syncthreads();
    if (t == 0) part[blockIdx.x] = wsum[0] + wsum[1] + wsum[2] + wsum[3];
}

__global__ __launch_bounds__(128) void scan_p2(int* __restrict__ part, int nb, int* __restrict__ off)
{
    __shared__ int wt[2];
    int t = threadIdx.x;
    int lane = t & 63, w = t >> 6;
    int v = (t < nb) ? part[t] : 0;
    int x = v;
    for (int d = 1; d < 64; d <<= 1) { int y = __shfl_up(x, d, 64); if (lane >= d) x += y; }
    if (lane == 63) wt[w] = x;
    __syncthreads();
    int base = (w == 1) ? wt[0] : 0;
    int excl = base + x - v;
    if (t < nb) part[t] = excl;
    if (t == 0) off[NN] = NEP;
}

__global__ __launch_bounds__(256) void scan_p3(int* __restrict__ data, const int* __restrict__ part, int n)
{
    __shared__ int wsum[4];
    int t = threadIdx.x, lane = t & 63, w = t >> 6;
    int i0 = blockIdx.x * 1024 + t * 4;
    int d0 = 0, d1 = 0, d2 = 0, d3 = 0;
    if (i0 + 3 < n) { int4 d = *(const int4*)(data + i0); d0 = d.x; d1 = d.y; d2 = d.z; d3 = d.w; }
    else if (i0 < n) {
        d0 = data[i0];
        if (i0 + 1 < n) d1 = data[i0 + 1];
        if (i0 + 2 < n) d2 = data[i0 + 2];
    }
    int s = d0 + d1 + d2 + d3;
    int x = s;
    for (int d = 1; d < 64; d <<= 1) { int y = __shfl_up(x, d, 64); if (lane >= d) x += y; }
    if (lane == 63) wsum[w] = x;
    __syncthreads();
    int wb = 0;
    for (int i = 0; i < w; i++) wb += wsum[i];
    int base = part[blockIdx.x] + wb + x - s;
    if (i0 < n)     data[i0]     = base;
    if (i0 + 1 < n) data[i0 + 1] = base + d0;
    if (i0 + 2 < n) data[i0 + 2] = base + d0 + d1;
    if (i0 + 3 < n) data[i0 + 3] = base + d0 + d1 + d2;
}

__global__ __launch_bounds__(256) void part_scatter(const int* __restrict__ ei,
                                                    const int* __restrict__ hist,
                                                    unsigned* __restrict__ ebuf)
{
    __shared__ int cur[NBUCK2];
    int tid = threadIdx.x, k = blockIdx.x;
    for (int i = tid; i < NBUCK2; i += 256) cur[i] = hist[i * NBLK + k];
    __syncthreads();
    int e0 = k * CHUNK, e1 = min(e0 + CHUNK, NEP);
    for (int e = e0 + tid; e < e1; e += 256) {
        int src, dst;
        if (e < NE) { src = ei[e]; dst = ei[NE + e]; } else { src = dst = e - NE; }
        int pos = atomicAdd(&cur[dst >> 8], 1);
        ebuf[pos] = (unsigned)src | ((unsigned)(dst & 255) << 24);
    }
}

__global__ __launch_bounds__(256) void bucket_csr(const int* __restrict__ hist,
                                                  const unsigned* __restrict__ ebuf,
                                                  int* __restrict__ off, int* __restrict__ csr)
{
    __shared__ int cnt[256];
    __shared__ int cur[256];
    __shared__ int wsum[4];
    int b = blockIdx.x;
    int d0 = b << 8;
    int tid = threadIdx.x;
    int e0 = hist[b * NBLK];
    int e1 = (b + 1 < NBUCK2) ? hist[(b + 1) * NBLK] : NEP;
    cnt[tid] = 0;
    __syncthreads();
    for (int i = e0 + tid; i < e1; i += 256) atomicAdd(&cnt[ebuf[i] >> 24], 1);
    __syncthreads();
    int c = cnt[tid];
    int x = c;
    int lane = tid & 63, w = tid >> 6;
    for (int d = 1; d < 64; d <<= 1) { int y = __shfl_up(x, d, 64); if (lane >= d) x += y; }
    if (lane == 63) wsum[w] = x;
    __syncthreads();
    int wb = 0;
    for (int i = 0; i < w; i++) wb += wsum[i];
    int excl = wb + x - c;
    cur[tid] = e0 + excl;
    int node = d0 + tid;
    if (node < NN) off[node] = e0 + excl;
    __syncthreads();
    for (int i = e0 + tid; i < e1; i += 256) {
        unsigned v = ebuf[i];
        int p = atomicAdd(&cur[v >> 24], 1);
        csr[p] = (int)(v & 0xFFFFFF);
    }
}

// ================= node feature prep (fp16 x [N][96]; bio + pca + pad fused) =================

__global__ __launch_bounds__(256) void bio_kernel(
    const float* __restrict__ xb, const float* __restrict__ xp,
    const float* __restrict__ W1, const float* __restrict__ b1,
    const float* __restrict__ g0, const float* __restrict__ bb0,
    const float* __restrict__ m0, const float* __restrict__ v0,
    const float* __restrict__ W2, const float* __restrict__ b2,
    __half* __restrict__ xh)
{
    __shared__ float sW1[16*64], sW2[16*16], sb1[16], sb2[16], ss[16], st[16];
    int tid = threadIdx.x;
    for (int idx = tid; idx < 1024; idx += 256) sW1[idx] = W1[idx];
    if (tid < 256) sW2[tid] = W2[tid];
    if (tid < 16) {
        sb1[tid] = b1[tid]; sb2[tid] = b2[tid];
        float s = g0[tid] * rsqrtf(v0[tid] + 1e-5f);
        ss[tid] = s; st[tid] = bb0[tid] - m0[tid] * s;
    }
    __syncthreads();
    int i = blockIdx.x * 256 + tid;
    if (i >= NN) return;
    float bio[64];
    const float4* p = (const float4*)(xb + (size_t)i * 64);
    #pragma unroll
    for (int q = 0; q < 16; q++) {
        float4 f = p[q];
        bio[q*4] = f.x; bio[q*4+1] = f.y; bio[q*4+2] = f.z; bio[q*4+3] = f.w;
    }
    float t1[16];
    #pragma unroll
    for (int j = 0; j < 16; j++) {
        float acc = sb1[j];
        #pragma unroll
        for (int k = 0; k < 64; k++) acc += bio[k] * sW1[j*64 + k];
        acc = acc * ss[j] + st[j];
        t1[j] = elu_f(acc);
    }
    __half* xrow = xh + (size_t)i * 96;
    const float* xpr = xp + (size_t)i * 50;
    #pragma unroll
    for (int j = 0; j < 25; j++) {
        float2 f = *(const float2*)(xpr + 2 * j);
        *(__half2*)(xrow + 2 * j) = __floats2half2_rn(f.x, f.y);
    }
    #pragma unroll
    for (int j = 0; j < 16; j++) {
        float acc = sb2[j];
        #pragma unroll
        for (int k = 0; k < 16; k++) acc += t1[k] * sW2[j*16 + k];
        xrow[50 + j] = __float2half(elu_f(acc));
    }
    __half2 z2 = __floats2half2_rn(0.f, 0.f);
    #pragma unroll
    for (int j = 0; j < 15; j++) *(__half2*)(xrow + 66 + 2 * j) = z2;
}

// ================= all weight conversions + BN/bias pre-fold in one launch =================

__global__ __launch_bounds__(256) void wconvert_all(
    const float* __restrict__ Wl1, const float* __restrict__ Wr1,
    const float* __restrict__ bl1, const float* __restrict__ br1,
    const float* __restrict__ Wl2, const float* __restrict__ Wr2,
    const float* __restrict__ bl2, const float* __restrict__ br2,
    const float* __restrict__ predW, const float* __restrict__ predb,
    const float* __restrict__ bias1, const float* __restrict__ bn1g,
    const float* __restrict__ bn1b, const float* __restrict__ bn1m,
    const float* __restrict__ bn1v,
    const float* __restrict__ bias2, const float* __restrict__ bn2g,
    const float* __restrict__ bn2b, const float* __restrict__ bn2m,
    const float* __restrict__ bn2v,
    __half* __restrict__ wcat1, float* __restrict__ bcat1,
    __half* __restrict__ wcat2, float* __restrict__ bcat2,
    __half* __restrict__ wpred, float* __restrict__ bpred,
    float* __restrict__ scb1, float* __restrict__ shb1,
    float* __restrict__ scb2, float* __restrict__ shb2)
{
    int t = blockIdx.x * 256 + threadIdx.x;
    if (t < 256 * 96) {
        int j = t / 96, k = t - j * 96;
        float v = (k < 66) ? ((j < 128) ? Wl1[j * 66 + k] : Wr1[(j - 128) * 66 + k]) : 0.f;
        wcat1[t] = __float2half(v);
    }
    int u = t - 256 * 96;
    if (u >= 0 && u < 64 * 128) {
        int j = u >> 7, k = u & 127;
        float v = (j < 32) ? Wl2[j * 128 + k] : Wr2[(j - 32) * 128 + k];
        wcat2[u] = __float2half(v);
    }
    int w = u - 64 * 128;
    if (w >= 0 && w < 64 * 32) {
        int j = w >> 5;
        wpred[w] = __float2half(j < 50 ? predW[w] : 0.f);
    }
    int z = w - 64 * 32;
    if (z >= 0 && z < 256) bcat1[z] = (z < 128) ? bl1[z] : br1[z - 128];
    int z2 = z - 256;
    if (z2 >= 0 && z2 < 64) bcat2[z2] = (z2 < 32) ? bl2[z2] : br2[z2 - 32];
    int z3 = z2 - 64;
    if (z3 >= 0 && z3 < 64) bpred[z3] = (z3 < 50) ? predb[z3] : 0.f;
    int z4 = z3 - 64;
    if (z4 >= 0 && z4 < 128) {
        float sc = bn1g[z4] * rsqrtf(bn1v[z4] + 1e-5f);
        scb1[z4] = sc;
        shb1[z4] = bn1b[z4] + (bias1[z4] - bn1m[z4]) * sc;
    }
    int z5 = z4 - 128;
    if (z5 >= 0 && z5 < 32) {
        float sc = bn2g[z5] * rsqrtf(bn2v[z5] + 1e-5f);
        scb2[z5] = sc;
        shb2[z5] = bn2b[z5] + (bias2[z5] - bn2m[z5]) * sc;
    }
}

// ================= MFMA f16 GEMM (column-blocked; split output at NSPL) =================
template<int KT, int NC, int NCB, int NSPL, bool FOUT>
__global__ __launch_bounds__(256) void mfma_gemm(
    const __half* __restrict__ in, const __half* __restrict__ wcat,
    const float* __restrict__ bcat, void* __restrict__ outv, void* __restrict__ outv2,
    int n, int ncol)
{
    constexpr int K = KT * 32;
    constexpr int KP = K + 8;
    __shared__ __half sW[NCB * KP];
    __shared__ __half sX[64 * KP];
    __shared__ float sB[NCB];
    int tid = threadIdx.x;
    int co = blockIdx.y * NCB;
    for (int idx = tid * 8; idx < NCB * K; idx += 256 * 8) {
        int r = idx / K, c = idx - r * K;
        *(half8*)(&sW[r * KP + c]) = *(const half8*)(&wcat[(size_t)(co + r) * K + c]);
    }
    for (int idx = tid; idx < NCB; idx += 256) sB[idx] = bcat[co + idx];
    int row0 = blockIdx.x * 64;
    half8 hz = {0, 0, 0, 0, 0, 0, 0, 0};
    for (int idx = tid * 8; idx < 64 * K; idx += 256 * 8) {
        int r = idx / K, c = idx - r * K;
        int gr = row0 + r;
        half8 v = (gr < n) ? *(const half8*)(&in[(size_t)gr * K + c]) : hz;
        *(half8*)(&sX[r * KP + c]) = v;
    }
    __syncthreads();
    int w = tid >> 6, lane = tid & 63;
    int m = lane & 15, quad = lane >> 4;
    half8 a[KT];
    #pragma unroll
    for (int kt = 0; kt < KT; kt++)
        a[kt] = *(const half8*)(&sX[(w * 16 + m) * KP + kt * 32 + quad * 8]);
    #pragma unroll 1
    for (int nt = 0; nt < NCB / 16; nt++) {
        float4v acc = {0.f, 0.f, 0.f, 0.f};
        #pragma unroll
        for (int kt = 0; kt < KT; kt++) {
            half8 bfrag = *(const half8*)(&sW[(nt * 16 + m) * KP + kt * 32 + quad * 8]);
            acc = __builtin_amdgcn_mfma_f32_16x16x32_f16(a[kt], bfrag, acc, 0, 0, 0);
        }
        int col = co + nt * 16 + m;
        float bias = sB[nt * 16 + m];
        #pragma unroll
        for (int i = 0; i < 4; i++) {
            int r = row0 + w * 16 + quad * 4 + i;
            if (r < n) {
                if (FOUT) { if (col < ncol) ((float*)outv)[(size_t)r * ncol + col] = acc[i] + bias; }
                else if (col < NSPL)
                    ((__half*)outv)[(size_t)r * NSPL + col] = __float2half(acc[i] + bias);
                else
                    ((__half*)outv2)[(size_t)r * (NC - NSPL) + (col - NSPL)] = __float2half(acc[i] + bias);
            }
        }
    }
}

// ================= fused GATv2 layer 1: 2 nodes/wave, 4 edges/iter/node =================
// xl [N][128] fp16 dense gather array; xr [N][128] streamed once per node.
// row=lane>>4 = edge slot, cl=lane&15, ch=8*cl. Head = 4-lane quad -> sum4_all.
// Wave interleaves nodes nA=2w, nB=2w+1 in one fused chunk loop: 8 gathers in
// flight (depth-2 x 2 nodes). Per-node edge order identical to the 1-node
// version -> bitwise-identical accumulation. Exhausted-node slots gather row 0
// (L1-hot) with valid=false. att pre-scaled by log2e; BN+bias pre-folded.
struct Acc1 { float a0,a1,a2,a3,a4,a5,a6,a7,dn; };

__device__ __forceinline__ void edge1(
    Acc1& s, half8 cur, bool valid,
    h2v xr01, h2v xr23, h2v xr45, h2v xr67,
    h2v a01, h2v a23, h2v a45, h2v a67, h2v c2)
{
    h2v xl01 = {cur[0], cur[1]}, xl23 = {cur[2], cur[3]};
    h2v xl45 = {cur[4], cur[5]}, xl67 = {cur[6], cur[7]};
    h2v s01 = xl01 + xr01, s23 = xl23 + xr23;
    h2v s45 = xl45 + xr45, s67 = xl67 + xr67;
    h2v l01 = hmax2v(s01, s01 * c2);
    h2v l23 = hmax2v(s23, s23 * c2);
    h2v l45 = hmax2v(s45, s45 * c2);
    h2v l67 = hmax2v(s67, s67 * c2);
    float pp = dot2f(l01, a01, dot2f(l23, a23, dot2f(l45, a45, dot2f(l67, a67, 0.f))));
    pp = sum4_all(pp);
    float wgt = valid ? ex2(pp) : 0.f;
    s.dn += wgt;
    s.a0 = fmaf((float)cur[0], wgt, s.a0);
    s.a1 = fmaf((float)cur[1], wgt, s.a1);
    s.a2 = fmaf((float)cur[2], wgt, s.a2);
    s.a3 = fmaf((float)cur[3], wgt, s.a3);
    s.a4 = fmaf((float)cur[4], wgt, s.a4);
    s.a5 = fmaf((float)cur[5], wgt, s.a5);
    s.a6 = fmaf((float)cur[6], wgt, s.a6);
    s.a7 = fmaf((float)cur[7], wgt, s.a7);
}

__device__ __forceinline__ void finish1(
    Acc1& s, int node, int row, int ch,
    const float* __restrict__ scb, const float* __restrict__ shb,
    __half* __restrict__ h1)
{
    s.a0 += __shfl_xor(s.a0, 16, 64); s.a0 += __shfl_xor(s.a0, 32, 64);
    s.a1 += __shfl_xor(s.a1, 16, 64); s.a1 += __shfl_xor(s.a1, 32, 64);
    s.a2 += __shfl_xor(s.a2, 16, 64); s.a2 += __shfl_xor(s.a2, 32, 64);
    s.a3 += __shfl_xor(s.a3, 16, 64); s.a3 += __shfl_xor(s.a3, 32, 64);
    s.a4 += __shfl_xor(s.a4, 16, 64); s.a4 += __shfl_xor(s.a4, 32, 64);
    s.a5 += __shfl_xor(s.a5, 16, 64); s.a5 += __shfl_xor(s.a5, 32, 64);
    s.a6 += __shfl_xor(s.a6, 16, 64); s.a6 += __shfl_xor(s.a6, 32, 64);
    s.a7 += __shfl_xor(s.a7, 16, 64); s.a7 += __shfl_xor(s.a7, 32, 64);
    s.dn += __shfl_xor(s.dn, 16, 64); s.dn += __shfl_xor(s.dn, 32, 64);
    if (row == 0) {
        float inv = 1.f / (s.dn + 1e-16f);
        float4 s0 = *(const float4*)(scb + ch), s1 = *(const float4*)(scb + ch + 4);
        float4 h0 = *(const float4*)(shb + ch), h1f = *(const float4*)(shb + ch + 4);
        float o[8];
        o[0] = elu_f(fmaf(s.a0 * inv, s0.x, h0.x));
        o[1] = elu_f(fmaf(s.a1 * inv, s0.y, h0.y));
        o[2] = elu_f(fmaf(s.a2 * inv, s0.z, h0.z));
        o[3] = elu_f(fmaf(s.a3 * inv, s0.w, h0.w));
        o[4] = elu_f(fmaf(s.a4 * inv, s1.x, h1f.x));
        o[5] = elu_f(fmaf(s.a5 * inv, s1.y, h1f.y));
        o[6] = elu_f(fmaf(s.a6 * inv, s1.z, h1f.z));
        o[7] = elu_f(fmaf(s.a7 * inv, s1.w, h1f.w));
        half8 oh = {(_Float16)o[0], (_Float16)o[1], (_Float16)o[2], (_Float16)o[3],
                    (_Float16)o[4], (_Float16)o[5], (_Float16)o[6], (_Float16)o[7]};
        *(half8*)(h1 + (size_t)node * 128 + ch) = oh;
    }
}

__global__ __launch_bounds__(256) void fused_gat1(
    const int* __restrict__ off, const int* __restrict__ csr,
    const __half* __restrict__ xl, const __half* __restrict__ xr,
    const float* __restrict__ att,
    const float* __restrict__ scb, const float* __restrict__ shb,
    __half* __restrict__ h1)
{
    int wave = threadIdx.x >> 6;
    int lane = threadIdx.x & 63;
    int nA = blockIdx.x * 8 + wave * 2;   // grid exact for NN=100000 (even): nB always < NN
    int nB = nA + 1;
    if (nA >= NN) return;
    int row = lane >> 4;
    int cl  = lane & 15;
    int ch  = cl * 8;
    unsigned chb = (unsigned)cl * 16u;
    const char* xbase = (const char*)xl;
    const float LOG2E = 1.44269504088896f;

    half8 xrA8 = *(const half8*)((const char*)xr + (size_t)nA * 256 + chb);
    half8 xrB8 = *(const half8*)((const char*)xr + (size_t)nB * 256 + chb);
    float4 af0 = *(const float4*)(att + ch);
    float4 af1 = *(const float4*)(att + ch + 4);
    h2v a01 = {(_Float16)(af0.x * LOG2E), (_Float16)(af0.y * LOG2E)};
    h2v a23 = {(_Float16)(af0.z * LOG2E), (_Float16)(af0.w * LOG2E)};
    h2v a45 = {(_Float16)(af1.x * LOG2E), (_Float16)(af1.y * LOG2E)};
    h2v a67 = {(_Float16)(af1.z * LOG2E), (_Float16)(af1.w * LOG2E)};
    h2v xA01 = {xrA8[0], xrA8[1]}, xA23 = {xrA8[2], xrA8[3]};
    h2v xA45 = {xrA8[4], xrA8[5]}, xA67 = {xrA8[6], xrA8[7]};
    h2v xB01 = {xrB8[0], xrB8[1]}, xB23 = {xrB8[2], xrB8[3]};
    h2v xB45 = {xrB8[4], xrB8[5]}, xB67 = {xrB8[6], xrB8[7]};
    const h2v c2 = {(_Float16)0.2f, (_Float16)0.2f};

    int baseA = off[nA];
    int kA1   = off[nA + 1];
    int baseB = kA1;                 // off[nB] == off[nA+1]
    int kB1   = off[nA + 2];

    Acc1 sA = {0.f,0.f,0.f,0.f,0.f,0.f,0.f,0.f,0.f};
    Acc1 sB = {0.f,0.f,0.f,0.f,0.f,0.f,0.f,0.f,0.f};

    int rowp4  = row + 4;
    int rowp8  = row + 8;
    int rowp12 = row + 12;

    while (baseA < kA1 || baseB < kB1) {
        int remA = kA1 - baseA, remB = kB1 - baseB;
        int nbA = remA > 0 ? min(64, remA) : 0;
        int nbB = remB > 0 ? min(64, remB) : 0;
        int srcA = (lane < nbA) ? csr[baseA + lane] : 0;
        int srcB = (lane < nbB) ? csr[baseB + lane] : 0;
        int nt = max(nbA, nbB);
        int iA0 = __shfl(srcA, row, 64),   iA1 = __shfl(srcA, rowp4, 64);
        int iB0 = __shfl(srcB, row, 64),   iB1 = __shfl(srcB, rowp4, 64);
        half8 cA0 = *(const half8*)(xbase + (((unsigned)iA0 << 8) + chb));
        half8 cA1 = *(const half8*)(xbase + (((unsigned)iA1 << 8) + chb));
        half8 cB0 = *(const half8*)(xbase + (((unsigned)iB0 << 8) + chb));
        half8 cB1 = *(const half8*)(xbase + (((unsigned)iB1 << 8) + chb));
        for (int t = 0; t < nt; t += 8) {
            int jA0 = __shfl(srcA, t + rowp8, 64);
            int jA1 = __shfl(srcA, t + rowp12, 64);
            int jB0 = __shfl(srcB, t + rowp8, 64);
            int jB1 = __shfl(srcB, t + rowp12, 64);
            half8 pA0 = *(const half8*)(xbase + (((unsigned)jA0 << 8) + chb));
            half8 pA1 = *(const half8*)(xbase + (((unsigned)jA1 << 8) + chb));
            half8 pB0 = *(const half8*)(xbase + (((unsigned)jB0 << 8) + chb));
            half8 pB1 = *(const half8*)(xbase + (((unsigned)jB1 << 8) + chb));
            edge1(sA, cA0, (t + row)   < nbA, xA01, xA23, xA45, xA67, a01, a23, a45, a67, c2);
            edge1(sA, cA1, (t + rowp4) < nbA, xA01, xA23, xA45, xA67, a01, a23, a45, a67, c2);
            edge1(sB, cB0, (t + row)   < nbB, xB01, xB23, xB45, xB67, a01, a23, a45, a67, c2);
            edge1(sB, cB1, (t + rowp4) < nbB, xB01, xB23, xB45, xB67, a01, a23, a45, a67, c2);
            cA0 = pA0; cA1 = pA1; cB0 = pB0; cB1 = pB1;
        }
        baseA += 64; baseB += 64;
    }
    finish1(sA, nA, row, ch, scb, shb, h1);
    finish1(sB, nB, row, ch, scb, shb, h1);
}

// ================= fused GATv2 layer 2: 2 nodes/wave, 8 edges/iter/node =================
// xl2 [N][32] fp16 dense gather array (64B rows), xr2 [N][32].
// row=lane>>3 = edge slot, cl=lane&7, ch=4*cl. Same 2-node interleave.
struct Acc2 { float a0,a1,a2,a3,dn; };

__device__ __forceinline__ void edge2(
    Acc2& s, h4v cur, bool valid,
    h2v xr01, h2v xr23, h2v a01, h2v a23, h2v c2)
{
    h2v xl01 = {cur[0], cur[1]}, xl23 = {cur[2], cur[3]};
    h2v s01 = xl01 + xr01, s23 = xl23 + xr23;
    h2v l01 = hmax2v(s01, s01 * c2);
    h2v l23 = hmax2v(s23, s23 * c2);
    float pp = dot2f(l01, a01, dot2f(l23, a23, 0.f));
    pp = sum8_all(pp);
    float wgt = valid ? ex2(pp) : 0.f;
    s.dn += wgt;
    s.a0 = fmaf((float)cur[0], wgt, s.a0);
    s.a1 = fmaf((float)cur[1], wgt, s.a1);
    s.a2 = fmaf((float)cur[2], wgt, s.a2);
    s.a3 = fmaf((float)cur[3], wgt, s.a3);
}

__device__ __forceinline__ void finish2(
    Acc2& s, int node, int row, int ch,
    const float* __restrict__ scb, const float* __restrict__ shb,
    __half* __restrict__ h2)
{
    s.a0 += __shfl_xor(s.a0, 8, 64); s.a0 += __shfl_xor(s.a0, 16, 64); s.a0 += __shfl_xor(s.a0, 32, 64);
    s.a1 += __shfl_xor(s.a1, 8, 64); s.a1 += __shfl_xor(s.a1, 16, 64); s.a1 += __shfl_xor(s.a1, 32, 64);
    s.a2 += __shfl_xor(s.a2, 8, 64); s.a2 += __shfl_xor(s.a2, 16, 64); s.a2 += __shfl_xor(s.a2, 32, 64);
    s.a3 += __shfl_xor(s.a3, 8, 64); s.a3 += __shfl_xor(s.a3, 16, 64); s.a3 += __shfl_xor(s.a3, 32, 64);
    s.dn += __shfl_xor(s.dn, 8, 64); s.dn += __shfl_xor(s.dn, 16, 64); s.dn += __shfl_xor(s.dn, 32, 64);
    if (row == 0) {
        float inv = 1.f / (s.dn + 1e-16f);
        float4 sv = *(const float4*)(scb + ch);
        float4 hv = *(const float4*)(shb + ch);
        float o0 = elu_f(fmaf(s.a0 * inv, sv.x, hv.x));
        float o1 = elu_f(fmaf(s.a1 * inv, sv.y, hv.y));
        float o2 = elu_f(fmaf(s.a2 * inv, sv.z, hv.z));
        float o3 = elu_f(fmaf(s.a3 * inv, sv.w, hv.w));
        h4v oh = {(_Float16)o0, (_Float16)o1, (_Float16)o2, (_Float16)o3};
        *(h4v*)(h2 + (size_t)node * 32 + ch) = oh;
    }
}

__global__ __launch_bounds__(256) void fused_gat2(
    const int* __restrict__ off, const int* __restrict__ csr,
    const __half* __restrict__ xl2, const __half* __restrict__ xr2,
    const float* __restrict__ att,
    const float* __restrict__ scb, const float* __restrict__ shb,
    __half* __restrict__ h2)
{
    int wave = threadIdx.x >> 6;
    int lane = threadIdx.x & 63;
    int nA = blockIdx.x * 8 + wave * 2;
    int nB = nA + 1;
    if (nA >= NN) return;
    int row = lane >> 3;
    int cl  = lane & 7;
    int ch  = cl * 4;
    unsigned chb = (unsigned)cl * 8u;
    const char* xbase = (const char*)xl2;
    const float LOG2E = 1.44269504088896f;

    h4v xrA4 = *(const h4v*)((const char*)xr2 + (size_t)nA * 64 + chb);
    h4v xrB4 = *(const h4v*)((const char*)xr2 + (size_t)nB * 64 + chb);
    h2v xA01 = {xrA4[0], xrA4[1]}, xA23 = {xrA4[2], xrA4[3]};
    h2v xB01 = {xrB4[0], xrB4[1]}, xB23 = {xrB4[2], xrB4[3]};
    float4 af = *(const float4*)(att + ch);
    h2v a01 = {(_Float16)(af.x * LOG2E), (_Float16)(af.y * LOG2E)};
    h2v a23 = {(_Float16)(af.z * LOG2E), (_Float16)(af.w * LOG2E)};
    const h2v c2 = {(_Float16)0.2f, (_Float16)0.2f};

    int baseA = off[nA];
    int kA1   = off[nA + 1];
    int baseB = kA1;
    int kB1   = off[nA + 2];

    Acc2 sA = {0.f,0.f,0.f,0.f,0.f};
    Acc2 sB = {0.f,0.f,0.f,0.f,0.f};

    int rowp8  = row + 8;
    int rowp16 = row + 16;
    int rowp24 = row + 24;

    while (baseA < kA1 || baseB < kB1) {
        int remA = kA1 - baseA, remB = kB1 - baseB;
        int nbA = remA > 0 ? min(64, remA) : 0;
        int nbB = remB > 0 ? min(64, remB) : 0;
        int srcA = (lane < nbA) ? csr[baseA + lane] : 0;
        int srcB = (lane < nbB) ? csr[baseB + lane] : 0;
        int nt = max(nbA, nbB);
        int iA0 = __shfl(srcA, row, 64),   iA1 = __shfl(srcA, rowp8, 64);
        int iB0 = __shfl(srcB, row, 64),   iB1 = __shfl(srcB, rowp8, 64);
        h4v cA0 = *(const h4v*)(xbase + (((unsigned)iA0 << 6) + chb));
        h4v cA1 = *(const h4v*)(xbase + (((unsigned)iA1 << 6) + chb));
        h4v cB0 = *(const h4v*)(xbase + (((unsigned)iB0 << 6) + chb));
        h4v cB1 = *(const h4v*)(xbase + (((unsigned)iB1 << 6) + chb));
        for (int t = 0; t < nt; t += 16) {
            int jA0 = __shfl(srcA, t + rowp16, 64);
            int jA1 = __shfl(srcA, t + rowp24, 64);
            int jB0 = __shfl(srcB, t + rowp16, 64);
            int jB1 = __shfl(srcB, t + rowp24, 64);
            h4v pA0 = *(const h4v*)(xbase + (((unsigned)jA0 << 6) + chb));
            h4v pA1 = *(const h4v*)(xbase + (((unsigned)jA1 << 6) + chb));
            h4v pB0 = *(const h4v*)(xbase + (((unsigned)jB0 << 6) + chb));
            h4v pB1 = *(const h4v*)(xbase + (((unsigned)jB1 << 6) + chb));
            edge2(sA, cA0, (t + row)   < nbA, xA01, xA23, a01, a23, c2);
            edge2(sA, cA1, (t + rowp8) < nbA, xA01, xA23, a01, a23, c2);
            edge2(sB, cB0, (t + row)   < nbB, xB01, xB23, a01, a23, c2);
            edge2(sB, cB1, (t + rowp8) < nbB, xB01, xB23, a01, a23, c2);
            cA0 = pA0; cA1 = pA1; cB0 = pB0; cB1 = pB1;
        }
        baseA += 64; baseB += 64;
    }
    finish2(sA, nA, row, ch, scb, shb, h2);
    finish2(sB, nB, row, ch, scb, shb, h2);
}

extern "C" void kernel_launch(void* const* d_in, const int* in_sizes, int n_in,
                              void* d_out, int out_size, void* d_ws, size_t ws_size,
                              hipStream_t stream)
{
    const float* x_pca = (const float*)d_in[0];
    const float* x_bio = (const float*)d_in[1];
    const int*   ei    = (const int*)d_in[2];
    const float* bioW1 = (const float*)d_in[3];
    const float* biob1 = (const float*)d_in[4];
    const float* bn0_g = (const float*)d_in[5];
    const float* bn0_b = (const float*)d_in[6];
    const float* bn0_m = (const float*)d_in[7];
    const float* bn0_v = (const float*)d_in[8];
    const float* bioW2 = (const float*)d_in[9];
    const float* biob2 = (const float*)d_in[10];
    const float* Wl1   = (const float*)d_in[11];
    const float* bl1   = (const float*)d_in[12];
    const float* Wr1   = (const float*)d_in[13];
    const float* br1   = (const float*)d_in[14];
    const float* att1  = (const float*)d_in[15];
    const float* bias1 = (const float*)d_in[16];
    const float* bn1_g = (const float*)d_in[17];
    const float* bn1_b = (const float*)d_in[18];
    const float* bn1_m = (const float*)d_in[19];
    const float* bn1_v = (const float*)d_in[20];
    const float* Wl2   = (const float*)d_in[21];
    const float* bl2   = (const float*)d_in[22];
    const float* Wr2   = (const float*)d_in[23];
    const float* br2   = (const float*)d_in[24];
    const float* att2  = (const float*)d_in[25];
    const float* bias2 = (const float*)d_in[26];
    const float* bn2_g = (const float*)d_in[27];
    const float* bn2_b = (const float*)d_in[28];
    const float* bn2_m = (const float*)d_in[29];
    const float* bn2_v = (const float*)d_in[30];
    const float* predW = (const float*)d_in[31];
    const float* predb = (const float*)d_in[32];

    __half* xh   = (__half*)d_ws;                      // N*96
    __half* xl1  = xh  + (size_t)NN * 96;              // N*128 (dense gather array)
    __half* xr1  = xl1 + (size_t)NN * 128;             // N*128
    __half* h1h  = xr1 + (size_t)NN * 128;             // N*128
    __half* xl2  = h1h + (size_t)NN * 128;             // N*32 (dense gather array)
    __half* xr2  = xl2 + (size_t)NN * 32;              // N*32
    __half* h2h  = xr2 + (size_t)NN * 32;              // N*32
    float*  p4   = (float*)(h2h + (size_t)NN * 32);
    __half* wcat1 = (__half*)p4;                       // 256*96 h
    float*  bcat1 = p4 + 12288;                        // 256
    __half* wcat2 = (__half*)(bcat1 + 256);            // 64*128 h
    float*  bcat2 = bcat1 + 256 + 4096;                // 64
    __half* wpred = (__half*)(bcat2 + 64);             // 64*32 h
    float*  bpred = bcat2 + 64 + 1024;                 // 64
    float*  scb1  = bpred + 64;                        // 128
    float*  shb1  = scb1 + 128;                        // 128
    float*  scb2  = shb1 + 128;                        // 32
    float*  shb2  = scb2 + 32;                         // 32
    int*    ib    = (int*)(shb2 + 32);
    unsigned* ebuf = (unsigned*)ib;                    // NEP
    int*    hist   = ib + NEP;                         // HISTN
    int*    part   = hist + HISTN;                     // 128
    int*    off    = part + 128;                       // NN+1
    int*    csr    = off + NN + 1;                     // NEP

    float* out = (float*)d_out;

    // ---- CSR build (deterministic radix partition) ----
    part_hist<<<NBLK, 256, 0, stream>>>(ei, hist);
    scan_p1<<<HSCAN_BLOCKS, 256, 0, stream>>>(hist, part, HISTN);
    scan_p2<<<1, 128, 0, stream>>>(part, HSCAN_BLOCKS, off);
    scan_p3<<<HSCAN_BLOCKS, 256, 0, stream>>>(hist, part, HISTN);
    part_scatter<<<NBLK, 256, 0, stream>>>(ei, hist, ebuf);
    bucket_csr<<<NBUCK2, 256, 0, stream>>>(hist, ebuf, off, csr);

    // ---- node features (fp16, pca+bio+pad fused) ----
    bio_kernel<<<(NN + 255) / 256, 256, 0, stream>>>(
        x_bio, x_pca, bioW1, biob1, bn0_g, bn0_b, bn0_m, bn0_v, bioW2, biob2, xh);

    // ---- all weight conversions + BN pre-fold ----
    wconvert_all<<<139, 256, 0, stream>>>(
        Wl1, Wr1, bl1, br1, Wl2, Wr2, bl2, br2, predW, predb,
        bias1, bn1_g, bn1_b, bn1_m, bn1_v,
        bias2, bn2_g, bn2_b, bn2_m, bn2_v,
        wcat1, bcat1, wcat2, bcat2, wpred, bpred,
        scb1, shb1, scb2, shb2);

    // ---- layer-1 transform (2 column blocks: y=0 -> xl1, y=1 -> xr1) ----
    mfma_gemm<3, 256, 128, 128, false><<<dim3((NN + 63) / 64, 2), 256, 0, stream>>>(
        xh, wcat1, bcat1, xl1, xr1, NN, 0);

    // ---- fused layer-1 edge phase (2 nodes/wave) ----
    fused_gat1<<<(NN + 7) / 8, 256, 0, stream>>>(
        off, csr, xl1, xr1, att1, scb1, shb1, h1h);

    // ---- layer-2 transform (split: xl cols 0..31, xr cols 32..63) ----
    mfma_gemm<4, 64, 64, 32, false><<<dim3((NN + 63) / 64, 1), 256, 0, stream>>>(
        h1h, wcat2, bcat2, xl2, xr2, NN, 0);

    // ---- fused layer-2 edge phase (2 nodes/wave) ----
    fused_gat2<<<(NN + 7) / 8, 256, 0, stream>>>(
        off, csr, xl2, xr2, att2, scb2, shb2, h2h);

    // ---- prediction head (MFMA, fp32 out) ----
    mfma_gemm<1, 64, 64, 64, true><<<dim3((NN + 63) / 64, 1), 256, 0, stream>>>(
        h2h, wpred, bpred, out, nullptr, NN, 50);
}

// Round 6
// 387.721 us; speedup vs baseline: 1.0658x; 1.0068x over previous
//
#include <hip/hip_runtime.h>
#include <hip/hip_fp16.h>
#include <cstdint>
#include <cstddef>

#define NN 100000
#define NE 1600000
#define NEP (NE + NN)              // 1,700,000
#define NBLK 200                   // partition blocks
#define CHUNK ((NEP + NBLK - 1) / NBLK)   // 8500
#define NBUCK2 ((NN + 255) / 256)  // 391 buckets of 256 dst nodes
#define HISTN (NBUCK2 * NBLK)      // 78,200
#define HSCAN_BLOCKS ((HISTN + 1023) / 1024)  // 77

typedef __attribute__((ext_vector_type(8))) _Float16 half8;
typedef __attribute__((ext_vector_type(4))) _Float16 h4v;
typedef __attribute__((ext_vector_type(2))) _Float16 h2v;
typedef __attribute__((ext_vector_type(4))) float float4v;

__device__ __forceinline__ float elu_f(float x) {
    return x > 0.f ? x : __expf(x) - 1.f;
}

__device__ __forceinline__ float ex2(float x) {
#if __has_builtin(__builtin_amdgcn_exp2f)
    return __builtin_amdgcn_exp2f(x);
#else
    return exp2f(x);
#endif
}

// ---- DPP reduce helpers (pure VALU) ----
template<int CTRL>
__device__ __forceinline__ float dpp_add(float x) {
    int s = __builtin_amdgcn_update_dpp(0, __float_as_int(x), CTRL, 0xF, 0xF, true);
    return x + __int_as_float(s);
}
// allsum within aligned 4-lane quads (one GAT1 head = 4 lanes x 8ch)
__device__ __forceinline__ float sum4_all(float x) {
    x = dpp_add<0xB1>(x); x = dpp_add<0x4E>(x);
    return x;
}
// allsum within aligned 8-lane groups (one GAT2 edge = 8 lanes x 4ch)
__device__ __forceinline__ float sum8_all(float x) {
    x = dpp_add<0xB1>(x); x = dpp_add<0x4E>(x); x = dpp_add<0x141>(x);
    return x;
}

__device__ __forceinline__ float dot2f(h2v a, h2v b, float c) {
#if __has_builtin(__builtin_amdgcn_fdot2)
    return __builtin_amdgcn_fdot2(a, b, c, false);
#else
    return fmaf((float)a[0], (float)b[0], fmaf((float)a[1], (float)b[1], c));
#endif
}

__device__ __forceinline__ h2v hmax2v(h2v a, h2v b) {
#if __has_builtin(__builtin_elementwise_max)
    return __builtin_elementwise_max(a, b);
#else
    __half2 r = __hmax2(*(__half2*)&a, *(__half2*)&b);
    return *(h2v*)&r;
#endif
}

// ================= CSR build: deterministic radix partition =================

__global__ __launch_bounds__(256) void part_hist(const int* __restrict__ ei, int* __restrict__ hist)
{
    __shared__ int cnt[NBUCK2];
    int tid = threadIdx.x, k = blockIdx.x;
    for (int i = tid; i < NBUCK2; i += 256) cnt[i] = 0;
    __syncthreads();
    int e0 = k * CHUNK, e1 = min(e0 + CHUNK, NEP);
    for (int e = e0 + tid; e < e1; e += 256) {
        int dst = (e < NE) ? ei[NE + e] : e - NE;
        atomicAdd(&cnt[dst >> 8], 1);
    }
    __syncthreads();
    for (int i = tid; i < NBUCK2; i += 256) hist[i * NBLK + k] = cnt[i];
}

__global__ __launch_bounds__(256) void scan_p1(const int* __restrict__ src, int* __restrict__ part, int n)
{
    __shared__ int wsum[4];
    int t = threadIdx.x;
    int i0 = blockIdx.x * 1024 + t * 4;
    int s = 0;
    if (i0 + 3 < n) { int4 d = *(const int4*)(src + i0); s = d.x + d.y + d.z + d.w; }
    else { for (int k = 0; k < 4; k++) if (i0 + k < n) s += src[i0 + k]; }
    for (int d = 1; d < 64; d <<= 1) s += __shfl_xor(s, d, 64);
    if ((t & 63) == 0) wsum[t >> 6] = s;
    __syncthreads();
    if (t == 0) part[blockIdx.x] = wsum[0] + wsum[1] + wsum[2] + wsum[3];
}

__global__ __launch_bounds__(128) void scan_p2(int* __restrict__ part, int nb, int* __restrict__ off)
{
    __shared__ int wt[2];
    int t = threadIdx.x;
    int lane = t & 63, w = t >> 6;
    int v = (t < nb) ? part[t] : 0;
    int x = v;
    for (int d = 1; d < 64; d <<= 1) { int y = __shfl_up(x, d, 64); if (lane >= d) x += y; }
    if (lane == 63) wt[w] = x;
    __syncthreads();
    int base = (w == 1) ? wt[0] : 0;
    int excl = base + x - v;
    if (t < nb) part[t] = excl;
    if (t == 0) off[NN] = NEP;
}

__global__ __launch_bounds__(256) void scan_p3(int* __restrict__ data, const int* __restrict__ part, int n)
{
    __shared__ int wsum[4];
    int t = threadIdx.x, lane = t & 63, w = t >> 6;
    int i0 = blockIdx.x * 1024 + t * 4;
    int d0 = 0, d1 = 0, d2 = 0, d3 = 0;
    if (i0 + 3 < n) { int4 d = *(const int4*)(data + i0); d0 = d.x; d1 = d.y; d2 = d.z; d3 = d.w; }
    else if (i0 < n) {
        d0 = data[i0];
        if (i0 + 1 < n) d1 = data[i0 + 1];
        if (i0 + 2 < n) d2 = data[i0 + 2];
    }
    int s = d0 + d1 + d2 + d3;
    int x = s;
    for (int d = 1; d < 64; d <<= 1) { int y = __shfl_up(x, d, 64); if (lane >= d) x += y; }
    if (lane == 63) wsum[w] = x;
    __syncthreads();
    int wb = 0;
    for (int i = 0; i < w; i++) wb += wsum[i];
    int base = part[blockIdx.x] + wb + x - s;
    if (i0 < n)     data[i0]     = base;
    if (i0 + 1 < n) data[i0 + 1] = base + d0;
    if (i0 + 2 < n) data[i0 + 2] = base + d0 + d1;
    if (i0 + 3 < n) data[i0 + 3] = base + d0 + d1 + d2;
}

__global__ __launch_bounds__(256) void part_scatter(const int* __restrict__ ei,
                                                    const int* __restrict__ hist,
                                                    unsigned* __restrict__ ebuf)
{
    __shared__ int cur[NBUCK2];
    int tid = threadIdx.x, k = blockIdx.x;
    for (int i = tid; i < NBUCK2; i += 256) cur[i] = hist[i * NBLK + k];
    __syncthreads();
    int e0 = k * CHUNK, e1 = min(e0 + CHUNK, NEP);
    for (int e = e0 + tid; e < e1; e += 256) {
        int src, dst;
        if (e < NE) { src = ei[e]; dst = ei[NE + e]; } else { src = dst = e - NE; }
        int pos = atomicAdd(&cur[dst >> 8], 1);
        ebuf[pos] = (unsigned)src | ((unsigned)(dst & 255) << 24);
    }
}

__global__ __launch_bounds__(256) void bucket_csr(const int* __restrict__ hist,
                                                  const unsigned* __restrict__ ebuf,
                                                  int* __restrict__ off, int* __restrict__ csr)
{
    __shared__ int cnt[256];
    __shared__ int cur[256];
    __shared__ int wsum[4];
    int b = blockIdx.x;
    int d0 = b << 8;
    int tid = threadIdx.x;
    int e0 = hist[b * NBLK];
    int e1 = (b + 1 < NBUCK2) ? hist[(b + 1) * NBLK] : NEP;
    cnt[tid] = 0;
    __syncthreads();
    for (int i = e0 + tid; i < e1; i += 256) atomicAdd(&cnt[ebuf[i] >> 24], 1);
    __syncthreads();
    int c = cnt[tid];
    int x = c;
    int lane = tid & 63, w = tid >> 6;
    for (int d = 1; d < 64; d <<= 1) { int y = __shfl_up(x, d, 64); if (lane >= d) x += y; }
    if (lane == 63) wsum[w] = x;
    __syncthreads();
    int wb = 0;
    for (int i = 0; i < w; i++) wb += wsum[i];
    int excl = wb + x - c;
    cur[tid] = e0 + excl;
    int node = d0 + tid;
    if (node < NN) off[node] = e0 + excl;
    __syncthreads();
    for (int i = e0 + tid; i < e1; i += 256) {
        unsigned v = ebuf[i];
        int p = atomicAdd(&cur[v >> 24], 1);
        csr[p] = (int)(v & 0xFFFFFF);
    }
}

// ===== merged: node feature prep (blocks 0..390) + weight conversions (391..529) =====

__global__ __launch_bounds__(256) void bio_wconv(
    const float* __restrict__ xb, const float* __restrict__ xp,
    const float* __restrict__ W1, const float* __restrict__ b1,
    const float* __restrict__ g0, const float* __restrict__ bb0,
    const float* __restrict__ m0, const float* __restrict__ v0,
    const float* __restrict__ W2, const float* __restrict__ b2,
    __half* __restrict__ xh,
    const float* __restrict__ Wl1, const float* __restrict__ Wr1,
    const float* __restrict__ bl1, const float* __restrict__ br1,
    const float* __restrict__ Wl2, const float* __restrict__ Wr2,
    const float* __restrict__ bl2, const float* __restrict__ br2,
    const float* __restrict__ predW, const float* __restrict__ predb,
    const float* __restrict__ bias1, const float* __restrict__ bn1g,
    const float* __restrict__ bn1b, const float* __restrict__ bn1m,
    const float* __restrict__ bn1v,
    const float* __restrict__ bias2, const float* __restrict__ bn2g,
    const float* __restrict__ bn2b, const float* __restrict__ bn2m,
    const float* __restrict__ bn2v,
    __half* __restrict__ wcat1, float* __restrict__ bcat1,
    __half* __restrict__ wcat2, float* __restrict__ bcat2,
    __half* __restrict__ wpred, float* __restrict__ bpred,
    float* __restrict__ scb1, float* __restrict__ shb1,
    float* __restrict__ scb2, float* __restrict__ shb2)
{
    __shared__ float sW1[16*64], sW2[16*16], sb1[16], sb2[16], ss[16], st[16];
    int tid = threadIdx.x;
    if (blockIdx.x < NBUCK2) {
        // ---- bio path ----
        for (int idx = tid; idx < 1024; idx += 256) sW1[idx] = W1[idx];
        if (tid < 256) sW2[tid] = W2[tid];
        if (tid < 16) {
            sb1[tid] = b1[tid]; sb2[tid] = b2[tid];
            float s = g0[tid] * rsqrtf(v0[tid] + 1e-5f);
            ss[tid] = s; st[tid] = bb0[tid] - m0[tid] * s;
        }
        __syncthreads();
        int i = blockIdx.x * 256 + tid;
        if (i >= NN) return;
        float bio[64];
        const float4* p = (const float4*)(xb + (size_t)i * 64);
        #pragma unroll
        for (int q = 0; q < 16; q++) {
            float4 f = p[q];
            bio[q*4] = f.x; bio[q*4+1] = f.y; bio[q*4+2] = f.z; bio[q*4+3] = f.w;
        }
        float t1[16];
        #pragma unroll
        for (int j = 0; j < 16; j++) {
            float acc = sb1[j];
            #pragma unroll
            for (int k = 0; k < 64; k++) acc += bio[k] * sW1[j*64 + k];
            acc = acc * ss[j] + st[j];
            t1[j] = elu_f(acc);
        }
        __half* xrow = xh + (size_t)i * 96;
        const float* xpr = xp + (size_t)i * 50;
        #pragma unroll
        for (int j = 0; j < 25; j++) {
            float2 f = *(const float2*)(xpr + 2 * j);
            *(__half2*)(xrow + 2 * j) = __floats2half2_rn(f.x, f.y);
        }
        #pragma unroll
        for (int j = 0; j < 16; j++) {
            float acc = sb2[j];
            #pragma unroll
            for (int k = 0; k < 16; k++) acc += t1[k] * sW2[j*16 + k];
            xrow[50 + j] = __float2half(elu_f(acc));
        }
        __half2 z2 = __floats2half2_rn(0.f, 0.f);
        #pragma unroll
        for (int j = 0; j < 15; j++) *(__half2*)(xrow + 66 + 2 * j) = z2;
    } else {
        // ---- weight-convert path ----
        int t = (blockIdx.x - NBUCK2) * 256 + tid;
        if (t < 256 * 96) {
            int j = t / 96, k = t - j * 96;
            float v = (k < 66) ? ((j < 128) ? Wl1[j * 66 + k] : Wr1[(j - 128) * 66 + k]) : 0.f;
            wcat1[t] = __float2half(v);
        }
        int u = t - 256 * 96;
        if (u >= 0 && u < 64 * 128) {
            int j = u >> 7, k = u & 127;
            float v = (j < 32) ? Wl2[j * 128 + k] : Wr2[(j - 32) * 128 + k];
            wcat2[u] = __float2half(v);
        }
        int w = u - 64 * 128;
        if (w >= 0 && w < 64 * 32) {
            int j = w >> 5;
            wpred[w] = __float2half(j < 50 ? predW[w] : 0.f);
        }
        int z = w - 64 * 32;
        if (z >= 0 && z < 256) bcat1[z] = (z < 128) ? bl1[z] : br1[z - 128];
        int z2 = z - 256;
        if (z2 >= 0 && z2 < 64) bcat2[z2] = (z2 < 32) ? bl2[z2] : br2[z2 - 32];
        int z3 = z2 - 64;
        if (z3 >= 0 && z3 < 64) bpred[z3] = (z3 < 50) ? predb[z3] : 0.f;
        int z4 = z3 - 64;
        if (z4 >= 0 && z4 < 128) {
            float sc = bn1g[z4] * rsqrtf(bn1v[z4] + 1e-5f);
            scb1[z4] = sc;
            shb1[z4] = bn1b[z4] + (bias1[z4] - bn1m[z4]) * sc;
        }
        int z5 = z4 - 128;
        if (z5 >= 0 && z5 < 32) {
            float sc = bn2g[z5] * rsqrtf(bn2v[z5] + 1e-5f);
            scb2[z5] = sc;
            shb2[z5] = bn2b[z5] + (bias2[z5] - bn2m[z5]) * sc;
        }
    }
}

// ================= MFMA f16 GEMM (column-blocked; split output at NSPL) =================
template<int KT, int NC, int NCB, int NSPL, bool FOUT>
__global__ __launch_bounds__(256) void mfma_gemm(
    const __half* __restrict__ in, const __half* __restrict__ wcat,
    const float* __restrict__ bcat, void* __restrict__ outv, void* __restrict__ outv2,
    int n, int ncol)
{
    constexpr int K = KT * 32;
    constexpr int KP = K + 8;
    __shared__ __half sW[NCB * KP];
    __shared__ __half sX[64 * KP];
    __shared__ float sB[NCB];
    int tid = threadIdx.x;
    int co = blockIdx.y * NCB;
    for (int idx = tid * 8; idx < NCB * K; idx += 256 * 8) {
        int r = idx / K, c = idx - r * K;
        *(half8*)(&sW[r * KP + c]) = *(const half8*)(&wcat[(size_t)(co + r) * K + c]);
    }
    for (int idx = tid; idx < NCB; idx += 256) sB[idx] = bcat[co + idx];
    int row0 = blockIdx.x * 64;
    half8 hz = {0, 0, 0, 0, 0, 0, 0, 0};
    for (int idx = tid * 8; idx < 64 * K; idx += 256 * 8) {
        int r = idx / K, c = idx - r * K;
        int gr = row0 + r;
        half8 v = (gr < n) ? *(const half8*)(&in[(size_t)gr * K + c]) : hz;
        *(half8*)(&sX[r * KP + c]) = v;
    }
    __syncthreads();
    int w = tid >> 6, lane = tid & 63;
    int m = lane & 15, quad = lane >> 4;
    half8 a[KT];
    #pragma unroll
    for (int kt = 0; kt < KT; kt++)
        a[kt] = *(const half8*)(&sX[(w * 16 + m) * KP + kt * 32 + quad * 8]);
    #pragma unroll 1
    for (int nt = 0; nt < NCB / 16; nt++) {
        float4v acc = {0.f, 0.f, 0.f, 0.f};
        #pragma unroll
        for (int kt = 0; kt < KT; kt++) {
            half8 bfrag = *(const half8*)(&sW[(nt * 16 + m) * KP + kt * 32 + quad * 8]);
            acc = __builtin_amdgcn_mfma_f32_16x16x32_f16(a[kt], bfrag, acc, 0, 0, 0);
        }
        int col = co + nt * 16 + m;
        float bias = sB[nt * 16 + m];
        #pragma unroll
        for (int i = 0; i < 4; i++) {
            int r = row0 + w * 16 + quad * 4 + i;
            if (r < n) {
                if (FOUT) { if (col < ncol) ((float*)outv)[(size_t)r * ncol + col] = acc[i] + bias; }
                else if (col < NSPL)
                    ((__half*)outv)[(size_t)r * NSPL + col] = __float2half(acc[i] + bias);
                else
                    ((__half*)outv2)[(size_t)r * (NC - NSPL) + (col - NSPL)] = __float2half(acc[i] + bias);
            }
        }
    }
}

// ================= fused GATv2 layer 1: 4 edges/iter x 16 lanes x 8ch =================
// xl [N][128] fp16 (dense gather array), xr [N][128] fp16 (streamed once/node).
// row=lane>>4 = edge slot, cl=lane&15, ch=8*cl. Head = 32 ch = 4 lanes -> sum4_all.
// 1 node/wave, depth-2 prefetch (the proven R4 structure: adding ILP beyond this
// costs occupancy and nets negative). No index clamps: invalid lanes gather row 0
// and the `valid` mask zeroes the weight. att pre-scaled by log2(e); BN pre-folded.
__global__ __launch_bounds__(256) void fused_gat1(
    const int* __restrict__ off, const int* __restrict__ csr,
    const __half* __restrict__ xl, const __half* __restrict__ xr,
    const float* __restrict__ att,
    const float* __restrict__ scb, const float* __restrict__ shb,
    __half* __restrict__ h1)
{
    int wave = threadIdx.x >> 6;
    int lane = threadIdx.x & 63;
    int node = blockIdx.x * 4 + wave;
    if (node >= NN) return;
    int row = lane >> 4;       // edge slot 0..3
    int cl  = lane & 15;
    int ch  = cl * 8;
    unsigned chb = (unsigned)cl * 16u;       // byte offset of my half8 in a 256B row
    const char* xbase = (const char*)xl;
    const float LOG2E = 1.44269504088896f;

    half8 xr8 = *(const half8*)((const char*)xr + (size_t)node * 256 + chb);
    float4 af0 = *(const float4*)(att + ch);
    float4 af1 = *(const float4*)(att + ch + 4);
    h2v a01 = {(_Float16)(af0.x * LOG2E), (_Float16)(af0.y * LOG2E)};
    h2v a23 = {(_Float16)(af0.z * LOG2E), (_Float16)(af0.w * LOG2E)};
    h2v a45 = {(_Float16)(af1.x * LOG2E), (_Float16)(af1.y * LOG2E)};
    h2v a67 = {(_Float16)(af1.z * LOG2E), (_Float16)(af1.w * LOG2E)};
    h2v xr01 = {xr8[0], xr8[1]}, xr23 = {xr8[2], xr8[3]};
    h2v xr45 = {xr8[4], xr8[5]}, xr67 = {xr8[6], xr8[7]};
    const h2v c2 = {(_Float16)0.2f, (_Float16)0.2f};

    int k0 = off[node], k1 = off[node + 1];
    float acc0 = 0.f, acc1 = 0.f, acc2 = 0.f, acc3 = 0.f;
    float acc4 = 0.f, acc5 = 0.f, acc6 = 0.f, acc7 = 0.f, denom = 0.f;

    int rowp4  = row + 4;
    int rowp8  = row + 8;
    int rowp12 = row + 12;

    auto edge = [&](half8 cur, bool valid) {
        h2v xl01 = {cur[0], cur[1]}, xl23 = {cur[2], cur[3]};
        h2v xl45 = {cur[4], cur[5]}, xl67 = {cur[6], cur[7]};
        h2v s01 = xl01 + xr01, s23 = xl23 + xr23;
        h2v s45 = xl45 + xr45, s67 = xl67 + xr67;
        h2v l01 = hmax2v(s01, s01 * c2);
        h2v l23 = hmax2v(s23, s23 * c2);
        h2v l45 = hmax2v(s45, s45 * c2);
        h2v l67 = hmax2v(s67, s67 * c2);
        float pp = dot2f(l01, a01, dot2f(l23, a23, dot2f(l45, a45, dot2f(l67, a67, 0.f))));
        pp = sum4_all(pp);                 // per-head (quad) logit (pre-scaled by log2e)
        float wgt = valid ? ex2(pp) : 0.f;
        denom += wgt;
        acc0 = fmaf((float)cur[0], wgt, acc0);
        acc1 = fmaf((float)cur[1], wgt, acc1);
        acc2 = fmaf((float)cur[2], wgt, acc2);
        acc3 = fmaf((float)cur[3], wgt, acc3);
        acc4 = fmaf((float)cur[4], wgt, acc4);
        acc5 = fmaf((float)cur[5], wgt, acc5);
        acc6 = fmaf((float)cur[6], wgt, acc6);
        acc7 = fmaf((float)cur[7], wgt, acc7);
    };

    for (int base = k0; base < k1; base += 64) {
        int nb = min(64, k1 - base);
        int mysrc = (lane < nb) ? csr[base + lane] : 0;
        int i0 = __shfl(mysrc, row, 64);
        int i1 = __shfl(mysrc, rowp4, 64);
        half8 c0 = *(const half8*)(xbase + (((unsigned)i0 << 8) + chb));
        half8 c1 = *(const half8*)(xbase + (((unsigned)i1 << 8) + chb));
        #pragma unroll 2
        for (int t = 0; t < nb; t += 8) {
            int i2 = __shfl(mysrc, t + rowp8, 64);
            int i3 = __shfl(mysrc, t + rowp12, 64);
            half8 cc2 = *(const half8*)(xbase + (((unsigned)i2 << 8) + chb));
            half8 cc3 = *(const half8*)(xbase + (((unsigned)i3 << 8) + chb));
            edge(c0, (t + row) < nb);
            edge(c1, (t + rowp4) < nb);
            c0 = cc2; c1 = cc3;
        }
    }
    // combine the 4 edge slots
    acc0 += __shfl_xor(acc0, 16, 64); acc0 += __shfl_xor(acc0, 32, 64);
    acc1 += __shfl_xor(acc1, 16, 64); acc1 += __shfl_xor(acc1, 32, 64);
    acc2 += __shfl_xor(acc2, 16, 64); acc2 += __shfl_xor(acc2, 32, 64);
    acc3 += __shfl_xor(acc3, 16, 64); acc3 += __shfl_xor(acc3, 32, 64);
    acc4 += __shfl_xor(acc4, 16, 64); acc4 += __shfl_xor(acc4, 32, 64);
    acc5 += __shfl_xor(acc5, 16, 64); acc5 += __shfl_xor(acc5, 32, 64);
    acc6 += __shfl_xor(acc6, 16, 64); acc6 += __shfl_xor(acc6, 32, 64);
    acc7 += __shfl_xor(acc7, 16, 64); acc7 += __shfl_xor(acc7, 32, 64);
    denom += __shfl_xor(denom, 16, 64); denom += __shfl_xor(denom, 32, 64);
    if (row == 0) {
        float inv = 1.f / (denom + 1e-16f);
        float4 s0 = *(const float4*)(scb + ch), s1 = *(const float4*)(scb + ch + 4);
        float4 h0 = *(const float4*)(shb + ch), h1f = *(const float4*)(shb + ch + 4);
        float o[8];
        o[0] = elu_f(fmaf(acc0 * inv, s0.x, h0.x));
        o[1] = elu_f(fmaf(acc1 * inv, s0.y, h0.y));
        o[2] = elu_f(fmaf(acc2 * inv, s0.z, h0.z));
        o[3] = elu_f(fmaf(acc3 * inv, s0.w, h0.w));
        o[4] = elu_f(fmaf(acc4 * inv, s1.x, h1f.x));
        o[5] = elu_f(fmaf(acc5 * inv, s1.y, h1f.y));
        o[6] = elu_f(fmaf(acc6 * inv, s1.z, h1f.z));
        o[7] = elu_f(fmaf(acc7 * inv, s1.w, h1f.w));
        half8 oh = {(_Float16)o[0], (_Float16)o[1], (_Float16)o[2], (_Float16)o[3],
                    (_Float16)o[4], (_Float16)o[5], (_Float16)o[6], (_Float16)o[7]};
        *(half8*)(h1 + (size_t)node * 128 + ch) = oh;
    }
}

// ================= fused GATv2 layer 2 + prediction head =================
// xl2 [N][32] fp16 dense gather array (64B rows), xr2 [N][32].
// row=lane>>3 = edge slot, cl=lane&7, ch=4*cl. 2 nodes/wave (measured win here,
// unlike gat1). After the slot reduction every lane holds the full h2 totals for
// its channel group -> fuse BN+ELU and the 32->50 pred matvec in-register:
// 16 shfl broadcasts + 16 dot2/lane, out written directly. No h2 materialization.
struct Acc2 { float a0,a1,a2,a3,dn; };

__device__ __forceinline__ void edge2(
    Acc2& s, h4v cur, bool valid,
    h2v xr01, h2v xr23, h2v a01, h2v a23, h2v c2)
{
    h2v xl01 = {cur[0], cur[1]}, xl23 = {cur[2], cur[3]};
    h2v s01 = xl01 + xr01, s23 = xl23 + xr23;
    h2v l01 = hmax2v(s01, s01 * c2);
    h2v l23 = hmax2v(s23, s23 * c2);
    float pp = dot2f(l01, a01, dot2f(l23, a23, 0.f));
    pp = sum8_all(pp);
    float wgt = valid ? ex2(pp) : 0.f;
    s.dn += wgt;
    s.a0 = fmaf((float)cur[0], wgt, s.a0);
    s.a1 = fmaf((float)cur[1], wgt, s.a1);
    s.a2 = fmaf((float)cur[2], wgt, s.a2);
    s.a3 = fmaf((float)cur[3], wgt, s.a3);
}

// reduce + BN + ELU; every lane returns the fp16 h2 values for its cl group
__device__ __forceinline__ h4v finish2v(
    Acc2& s, int ch,
    const float* __restrict__ scb, const float* __restrict__ shb)
{
    s.a0 += __shfl_xor(s.a0, 8, 64); s.a0 += __shfl_xor(s.a0, 16, 64); s.a0 += __shfl_xor(s.a0, 32, 64);
    s.a1 += __shfl_xor(s.a1, 8, 64); s.a1 += __shfl_xor(s.a1, 16, 64); s.a1 += __shfl_xor(s.a1, 32, 64);
    s.a2 += __shfl_xor(s.a2, 8, 64); s.a2 += __shfl_xor(s.a2, 16, 64); s.a2 += __shfl_xor(s.a2, 32, 64);
    s.a3 += __shfl_xor(s.a3, 8, 64); s.a3 += __shfl_xor(s.a3, 16, 64); s.a3 += __shfl_xor(s.a3, 32, 64);
    s.dn += __shfl_xor(s.dn, 8, 64); s.dn += __shfl_xor(s.dn, 16, 64); s.dn += __shfl_xor(s.dn, 32, 64);
    float inv = 1.f / (s.dn + 1e-16f);
    float4 sv = *(const float4*)(scb + ch);
    float4 hv = *(const float4*)(shb + ch);
    float o0 = elu_f(fmaf(s.a0 * inv, sv.x, hv.x));
    float o1 = elu_f(fmaf(s.a1 * inv, sv.y, hv.y));
    float o2 = elu_f(fmaf(s.a2 * inv, sv.z, hv.z));
    float o3 = elu_f(fmaf(s.a3 * inv, sv.w, hv.w));
    h4v oh = {(_Float16)o0, (_Float16)o1, (_Float16)o2, (_Float16)o3};
    return oh;
}

// pred matvec: lane o (<50) computes out[node][o] = sum_c h2[c]*Wp[o][c] + bp[o]
__device__ __forceinline__ void predstore(
    h4v oh, int node, int lane,
    half8 w0, half8 w1, half8 w2, half8 w3,
    float bp, float* __restrict__ out)
{
    int2 u = *(int2*)&oh;          // u.x = ch(0,1), u.y = ch(2,3) packed fp16
    float acc = 0.f;
#define PREDK(k, wv, r) { int b0 = __shfl(u.x, k, 64); int b1 = __shfl(u.y, k, 64); \
    h2v h01 = *(h2v*)&b0, h23 = *(h2v*)&b1; \
    h2v w01 = {wv[r], wv[r+1]}, w23 = {wv[r+2], wv[r+3]}; \
    acc = dot2f(h01, w01, acc); acc = dot2f(h23, w23, acc); }
    PREDK(0, w0, 0) PREDK(1, w0, 4)
    PREDK(2, w1, 0) PREDK(3, w1, 4)
    PREDK(4, w2, 0) PREDK(5, w2, 4)
    PREDK(6, w3, 0) PREDK(7, w3, 4)
#undef PREDK
    if (lane < 50) out[(size_t)node * 50 + lane] = acc + bp;
}

__global__ __launch_bounds__(256) void fused_gat2(
    const int* __restrict__ off, const int* __restrict__ csr,
    const __half* __restrict__ xl2, const __half* __restrict__ xr2,
    const float* __restrict__ att,
    const float* __restrict__ scb, const float* __restrict__ shb,
    const __half* __restrict__ wpred, const float* __restrict__ bpred,
    float* __restrict__ out)
{
    int wave = threadIdx.x >> 6;
    int lane = threadIdx.x & 63;
    int nA = blockIdx.x * 8 + wave * 2;   // NN even -> nB < NN whenever nA < NN
    int nB = nA + 1;
    if (nA >= NN) return;
    int row = lane >> 3;
    int cl  = lane & 7;
    int ch  = cl * 4;
    unsigned chb = (unsigned)cl * 8u;
    const char* xbase = (const char*)xl2;
    const float LOG2E = 1.44269504088896f;

    h4v xrA4 = *(const h4v*)((const char*)xr2 + (size_t)nA * 64 + chb);
    h4v xrB4 = *(const h4v*)((const char*)xr2 + (size_t)nB * 64 + chb);
    h2v xA01 = {xrA4[0], xrA4[1]}, xA23 = {xrA4[2], xrA4[3]};
    h2v xB01 = {xrB4[0], xrB4[1]}, xB23 = {xrB4[2], xrB4[3]};
    float4 af = *(const float4*)(att + ch);
    h2v a01 = {(_Float16)(af.x * LOG2E), (_Float16)(af.y * LOG2E)};
    h2v a23 = {(_Float16)(af.z * LOG2E), (_Float16)(af.w * LOG2E)};
    const h2v c2 = {(_Float16)0.2f, (_Float16)0.2f};

    // pred weights for my output column (rows >=50 are zero-padded)
    const __half* wrow = wpred + lane * 32;
    half8 w0 = *(const half8*)(wrow);
    half8 w1 = *(const half8*)(wrow + 8);
    half8 w2 = *(const half8*)(wrow + 16);
    half8 w3 = *(const half8*)(wrow + 24);
    float bp = (lane < 50) ? bpred[lane] : 0.f;

    int baseA = off[nA];
    int kA1   = off[nA + 1];
    int baseB = kA1;
    int kB1   = off[nA + 2];

    Acc2 sA = {0.f,0.f,0.f,0.f,0.f};
    Acc2 sB = {0.f,0.f,0.f,0.f,0.f};

    int rowp8  = row + 8;
    int rowp16 = row + 16;
    int rowp24 = row + 24;

    while (baseA < kA1 || baseB < kB1) {
        int remA = kA1 - baseA, remB = kB1 - baseB;
        int nbA = remA > 0 ? min(64, remA) : 0;
        int nbB = remB > 0 ? min(64, remB) : 0;
        int srcA = (lane < nbA) ? csr[baseA + lane] : 0;
        int srcB = (lane < nbB) ? csr[baseB + lane] : 0;
        int nt = max(nbA, nbB);
        int iA0 = __shfl(srcA, row, 64),   iA1 = __shfl(srcA, rowp8, 64);
        int iB0 = __shfl(srcB, row, 64),   iB1 = __shfl(srcB, rowp8, 64);
        h4v cA0 = *(const h4v*)(xbase + (((unsigned)iA0 << 6) + chb));
        h4v cA1 = *(const h4v*)(xbase + (((unsigned)iA1 << 6) + chb));
        h4v cB0 = *(const h4v*)(xbase + (((unsigned)iB0 << 6) + chb));
        h4v cB1 = *(const h4v*)(xbase + (((unsigned)iB1 << 6) + chb));
        for (int t = 0; t < nt; t += 16) {
            int jA0 = __shfl(srcA, t + rowp16, 64);
            int jA1 = __shfl(srcA, t + rowp24, 64);
            int jB0 = __shfl(srcB, t + rowp16, 64);
            int jB1 = __shfl(srcB, t + rowp24, 64);
            h4v pA0 = *(const h4v*)(xbase + (((unsigned)jA0 << 6) + chb));
            h4v pA1 = *(const h4v*)(xbase + (((unsigned)jA1 << 6) + chb));
            h4v pB0 = *(const h4v*)(xbase + (((unsigned)jB0 << 6) + chb));
            h4v pB1 = *(const h4v*)(xbase + (((unsigned)jB1 << 6) + chb));
            edge2(sA, cA0, (t + row)   < nbA, xA01, xA23, a01, a23, c2);
            edge2(sA, cA1, (t + rowp8) < nbA, xA01, xA23, a01, a23, c2);
            edge2(sB, cB0, (t + row)   < nbB, xB01, xB23, a01, a23, c2);
            edge2(sB, cB1, (t + rowp8) < nbB, xB01, xB23, a01, a23, c2);
            cA0 = pA0; cA1 = pA1; cB0 = pB0; cB1 = pB1;
        }
        baseA += 64; baseB += 64;
    }
    h4v ohA = finish2v(sA, ch, scb, shb);
    h4v ohB = finish2v(sB, ch, scb, shb);
    predstore(ohA, nA, lane, w0, w1, w2, w3, bp, out);
    predstore(ohB, nB, lane, w0, w1, w2, w3, bp, out);
}

extern "C" void kernel_launch(void* const* d_in, const int* in_sizes, int n_in,
                              void* d_out, int out_size, void* d_ws, size_t ws_size,
                              hipStream_t stream)
{
    const float* x_pca = (const float*)d_in[0];
    const float* x_bio = (const float*)d_in[1];
    const int*   ei    = (const int*)d_in[2];
    const float* bioW1 = (const float*)d_in[3];
    const float* biob1 = (const float*)d_in[4];
    const float* bn0_g = (const float*)d_in[5];
    const float* bn0_b = (const float*)d_in[6];
    const float* bn0_m = (const float*)d_in[7];
    const float* bn0_v = (const float*)d_in[8];
    const float* bioW2 = (const float*)d_in[9];
    const float* biob2 = (const float*)d_in[10];
    const float* Wl1   = (const float*)d_in[11];
    const float* bl1   = (const float*)d_in[12];
    const float* Wr1   = (const float*)d_in[13];
    const float* br1   = (const float*)d_in[14];
    const float* att1  = (const float*)d_in[15];
    const float* bias1 = (const float*)d_in[16];
    const float* bn1_g = (const float*)d_in[17];
    const float* bn1_b = (const float*)d_in[18];
    const float* bn1_m = (const float*)d_in[19];
    const float* bn1_v = (const float*)d_in[20];
    const float* Wl2   = (const float*)d_in[21];
    const float* bl2   = (const float*)d_in[22];
    const float* Wr2   = (const float*)d_in[23];
    const float* br2   = (const float*)d_in[24];
    const float* att2  = (const float*)d_in[25];
    const float* bias2 = (const float*)d_in[26];
    const float* bn2_g = (const float*)d_in[27];
    const float* bn2_b = (const float*)d_in[28];
    const float* bn2_m = (const float*)d_in[29];
    const float* bn2_v = (const float*)d_in[30];
    const float* predW = (const float*)d_in[31];
    const float* predb = (const float*)d_in[32];

    __half* xh   = (__half*)d_ws;                      // N*96
    __half* xl1  = xh  + (size_t)NN * 96;              // N*128 (dense gather array)
    __half* xr1  = xl1 + (size_t)NN * 128;             // N*128
    __half* h1h  = xr1 + (size_t)NN * 128;             // N*128
    __half* xl2  = h1h + (size_t)NN * 128;             // N*32 (dense gather array)
    __half* xr2  = xl2 + (size_t)NN * 32;              // N*32
    float*  p4   = (float*)(xr2 + (size_t)NN * 32);
    __half* wcat1 = (__half*)p4;                       // 256*96 h
    float*  bcat1 = p4 + 12288;                        // 256
    __half* wcat2 = (__half*)(bcat1 + 256);            // 64*128 h
    float*  bcat2 = bcat1 + 256 + 4096;                // 64
    __half* wpred = (__half*)(bcat2 + 64);             // 64*32 h
    float*  bpred = bcat2 + 64 + 1024;                 // 64
    float*  scb1  = bpred + 64;                        // 128
    float*  shb1  = scb1 + 128;                        // 128
    float*  scb2  = shb1 + 128;                        // 32
    float*  shb2  = scb2 + 32;                         // 32
    int*    ib    = (int*)(shb2 + 32);
    unsigned* ebuf = (unsigned*)ib;                    // NEP
    int*    hist   = ib + NEP;                         // HISTN
    int*    part   = hist + HISTN;                     // 128
    int*    off    = part + 128;                       // NN+1
    int*    csr    = off + NN + 1;                     // NEP

    float* out = (float*)d_out;

    // ---- CSR build (deterministic radix partition) ----
    part_hist<<<NBLK, 256, 0, stream>>>(ei, hist);
    scan_p1<<<HSCAN_BLOCKS, 256, 0, stream>>>(hist, part, HISTN);
    scan_p2<<<1, 128, 0, stream>>>(part, HSCAN_BLOCKS, off);
    scan_p3<<<HSCAN_BLOCKS, 256, 0, stream>>>(hist, part, HISTN);
    part_scatter<<<NBLK, 256, 0, stream>>>(ei, hist, ebuf);
    bucket_csr<<<NBUCK2, 256, 0, stream>>>(hist, ebuf, off, csr);

    // ---- node features + all weight conversions (merged) ----
    bio_wconv<<<NBUCK2 + 139, 256, 0, stream>>>(
        x_bio, x_pca, bioW1, biob1, bn0_g, bn0_b, bn0_m, bn0_v, bioW2, biob2, xh,
        Wl1, Wr1, bl1, br1, Wl2, Wr2, bl2, br2, predW, predb,
        bias1, bn1_g, bn1_b, bn1_m, bn1_v,
        bias2, bn2_g, bn2_b, bn2_m, bn2_v,
        wcat1, bcat1, wcat2, bcat2, wpred, bpred,
        scb1, shb1, scb2, shb2);

    // ---- layer-1 transform (2 column blocks: y=0 -> xl1, y=1 -> xr1) ----
    mfma_gemm<3, 256, 128, 128, false><<<dim3((NN + 63) / 64, 2), 256, 0, stream>>>(
        xh, wcat1, bcat1, xl1, xr1, NN, 0);

    // ---- fused layer-1 edge phase (1 node/wave, depth-2) ----
    fused_gat1<<<(NN + 3) / 4, 256, 0, stream>>>(
        off, csr, xl1, xr1, att1, scb1, shb1, h1h);

    // ---- layer-2 transform (split: xl cols 0..31, xr cols 32..63) ----
    mfma_gemm<4, 64, 64, 32, false><<<dim3((NN + 63) / 64, 1), 256, 0, stream>>>(
        h1h, wcat2, bcat2, xl2, xr2, NN, 0);

    // ---- fused layer-2 edge phase + prediction head (2 nodes/wave) ----
    fused_gat2<<<(NN + 7) / 8, 256, 0, stream>>>(
        off, csr, xl2, xr2, att2, scb2, shb2, wpred, bpred, out);
}